// Round 9
// baseline (1481.130 us; speedup 1.0000x reference)
//
#include <hip/hip_runtime.h>
#include <hip/hip_bf16.h>

typedef float f32x4 __attribute__((ext_vector_type(4)));
typedef short s16x8 __attribute__((ext_vector_type(8)));
typedef unsigned int u32x4 __attribute__((ext_vector_type(4)));

#define DEV static __device__ __forceinline__

DEV unsigned short f2bf(float x){
    unsigned u = __builtin_bit_cast(unsigned, x);
    u += 0x7FFFu + ((u >> 16) & 1u);
    return (unsigned short)(u >> 16);
}
DEV float bf2f(unsigned short h){
    unsigned u = ((unsigned)h) << 16;
    return __builtin_bit_cast(float, u);
}
DEV float sigm_(float x){ return __builtin_amdgcn_rcpf(1.0f + __expf(-x)); }
DEV float silu_(float x){ return x * sigm_(x); }

// ---------------- weight transpose + convert:  src [B][K][64] f32 -> dst [B][64][K] bf16
__global__ __launch_bounds__(256) void k_transconv(const float* __restrict__ src,
                                                   unsigned short* __restrict__ dst,
                                                   int K, int total){
    int gid = blockIdx.x * 256 + threadIdx.x;
    if (gid >= total) return;
    int kn  = K * 64;
    int b   = gid / kn;
    int rem = gid - b * kn;
    int k   = rem >> 6, n = rem & 63;
    dst[b * kn + n * K + k] = f2bf(src[gid]);
}

// ---------------- atom embedding gather
__global__ __launch_bounds__(256) void k_embed(const float* __restrict__ emb,
                                               const int* __restrict__ z,
                                               unsigned short* __restrict__ out){
    int gid = blockIdx.x * 256 + threadIdx.x;
    int n = gid >> 6, f = gid & 63;
    out[gid] = f2bf(emb[z[n] * 64 + f]);
}

// ---------------- bases[rows][9] @ W[9][64] -> bf16 out[rows][64]
__global__ __launch_bounds__(256) void k_smallmm(const float* __restrict__ bases,
                                                 const float* __restrict__ W,
                                                 unsigned short* __restrict__ out){
    int gid = blockIdx.x * 256 + threadIdx.x;
    int r = gid >> 6, f = gid & 63;
    const float* b = bases + r * 9;
    float acc = 0.f;
    #pragma unroll
    for (int k = 0; k < 9; ++k) acc += b[k] * W[k * 64 + f];
    out[gid] = f2bf(acc);
}

// ---------------- CSR build helpers
__global__ void k_count(const int* __restrict__ dst, int stride, int n, int* __restrict__ cnt){
    int i = blockIdx.x * 256 + threadIdx.x;
    if (i < n) atomicAdd(&cnt[dst[(size_t)i * stride]], 1);
}

__global__ __launch_bounds__(256) void k_bsum(const int* __restrict__ cnt,
                                              int* __restrict__ bsum){
    int i = blockIdx.x * 256 + threadIdx.x;
    int v = cnt[i];
    #pragma unroll
    for (int off = 32; off > 0; off >>= 1) v += __shfl_down(v, off);
    __shared__ int ws[4];
    if ((threadIdx.x & 63) == 0) ws[threadIdx.x >> 6] = v;
    __syncthreads();
    if (threadIdx.x == 0) bsum[blockIdx.x] = ws[0] + ws[1] + ws[2] + ws[3];
}

__global__ __launch_bounds__(256) void k_bscan(const int* __restrict__ bsum,
                                               int* __restrict__ bbase, int nb,
                                               int* __restrict__ total_out){
    __shared__ int sh[256];
    int t = threadIdx.x;
    int v = (t < nb) ? bsum[t] : 0;
    sh[t] = v;
    __syncthreads();
    for (int d = 1; d < 256; d <<= 1){
        int u = (t >= d) ? sh[t - d] : 0;
        __syncthreads();
        sh[t] += u;
        __syncthreads();
    }
    if (t < nb) bbase[t] = sh[t] - v;
    if (t == nb - 1) *total_out = sh[t];
}

__global__ __launch_bounds__(256) void k_offs(const int* __restrict__ cnt,
                                              const int* __restrict__ bbase,
                                              int* __restrict__ offs){
    __shared__ int sh[256];
    int t = threadIdx.x;
    int i = blockIdx.x * 256 + t;
    int v = cnt[i];
    sh[t] = v;
    __syncthreads();
    for (int d = 1; d < 256; d <<= 1){
        int u = (t >= d) ? sh[t - d] : 0;
        __syncthreads();
        sh[t] += u;
        __syncthreads();
    }
    offs[i] = bbase[blockIdx.x] + sh[t] - v;
}

__global__ void k_fill(const int* __restrict__ dst, int stride, int n,
                       const int* __restrict__ offs, int* __restrict__ cur,
                       int* __restrict__ idx){
    int i = blockIdx.x * 256 + threadIdx.x;
    if (i < n){
        int d = dst[(size_t)i * stride];
        int p = offs[d] + atomicAdd(&cur[d], 1);
        idx[p] = i;
    }
}

// ---------------- gather-reduce (contiguous): act[row] += sum_{j in [offs[row],offs[row+1])} upd[j]
__global__ __launch_bounds__(256) void k_reduce(const unsigned short* __restrict__ upd,
                                                const int* __restrict__ offs,
                                                unsigned short* __restrict__ act, int nRows){
    int gid = blockIdx.x * 256 + threadIdx.x;
    int row = gid >> 3;
    if (row >= nRows) return;
    int c8 = (gid & 7) * 8;
    int o = offs[row], e = offs[row + 1];
    float acc[8] = {};
    for (int j = o; j < e; ++j){
        s16x8 v = *(const s16x8*)&upd[(size_t)j * 64 + c8];
        #pragma unroll
        for (int q = 0; q < 8; ++q) acc[q] += bf2f((unsigned short)v[q]);
    }
    s16x8 a = *(s16x8*)&act[(size_t)row * 64 + c8];
    #pragma unroll
    for (int q = 0; q < 8; ++q) a[q] = (short)f2bf(bf2f((unsigned short)a[q]) + acc[q]);
    *(s16x8*)&act[(size_t)row * 64 + c8] = a;
}

#define MFMA16(a,b,c) __builtin_amdgcn_mfma_f32_16x16x32_bf16(a,b,c,0,0,0)

// ---------------- atom conv: barrier-free, wave owns 16 rows (all 64 cols)
__global__ __launch_bounds__(256, 4) void k_atom_conv(
    const unsigned short* __restrict__ atomBf, const unsigned short* __restrict__ bondBf,
    const unsigned short* __restrict__ bwagBf,
    const int* __restrict__ agraph, const int* __restrict__ d2u,
    const int* __restrict__ idxA,
    const unsigned short* __restrict__ w1cT, const unsigned short* __restrict__ w1gT,
    const unsigned short* __restrict__ w2cT, const unsigned short* __restrict__ w2gT,
    const unsigned short* __restrict__ woT,
    const float* __restrict__ cb1, const float* __restrict__ cb2,
    const float* __restrict__ gb1, const float* __restrict__ gb2,
    unsigned short* __restrict__ upd)
{
    __shared__ unsigned short ldsA[64 * 200];   // per-wave 16-row regions; H/V overlay after L1
    const int tid   = threadIdx.x;
    const int lane  = tid & 63, wid = tid >> 6;
    const int r16   = lane & 15, grp = lane >> 4;
    const int lane8 = lane & 7;
    const int wrow0 = blockIdx.x * 64 + wid * 16;

    // stage this wave's 16 rows x 3 sources (8 lanes per 128B row, 6 passes)
    #pragma unroll
    for (int p = 0; p < 6; ++p){
        int cc = p * 8 + (lane >> 3);
        int row16 = cc & 15, q = cc >> 4;
        int e = idxA[wrow0 + row16];
        const unsigned short* src;
        if (q == 0)      src = atomBf + (size_t)agraph[2 * e] * 64;
        else if (q == 1) src = bondBf + (size_t)d2u[e] * 64;
        else             src = atomBf + (size_t)agraph[2 * e + 1] * 64;
        *(u32x4*)&ldsA[(wid * 16 + row16) * 200 + q * 64 + lane8 * 8] =
            *(const u32x4*)(src + lane8 * 8);
    }
    // bw source rows for the 4 output rows this lane covers
    int ubw[4];
    #pragma unroll
    for (int j = 0; j < 4; ++j) ubw[j] = d2u[idxA[wrow0 + grp * 4 + j]];

    float c1b[4], g1b[4], c2b[4], g2b[4];
    #pragma unroll
    for (int n = 0; n < 4; ++n){
        c1b[n] = cb1[n * 16 + r16]; g1b[n] = gb1[n * 16 + r16];
        c2b[n] = cb2[n * 16 + r16]; g2b[n] = gb2[n * 16 + r16];
    }

    const unsigned short* Arow = ldsA + (wid * 16 + r16) * 200;
    f32x4 aC[4] = {}, aG[4] = {};
    #pragma unroll
    for (int kt = 0; kt < 6; ++kt){
        s16x8 a = *(const s16x8*)&Arow[kt * 32 + grp * 8];
        #pragma unroll
        for (int n = 0; n < 4; ++n){
            s16x8 bc = *(const s16x8*)&w1cT[(n * 16 + r16) * 192 + kt * 32 + grp * 8];
            s16x8 bg = *(const s16x8*)&w1gT[(n * 16 + r16) * 192 + kt * 32 + grp * 8];
            aC[n] = MFMA16(a, bc, aC[n]);
            aG[n] = MFMA16(a, bg, aG[n]);
        }
    }

    // per-wave hidden overlay in own region (stride 66; HC:0 HG:16*66 V:32*66)
    unsigned short* H = ldsA + wid * 16 * 200;
    #pragma unroll
    for (int n = 0; n < 4; ++n){
        #pragma unroll
        for (int j = 0; j < 4; ++j){
            int row16 = grp * 4 + j;
            H[row16 * 66 + n * 16 + r16]           = f2bf(silu_(aC[n][j] + c1b[n]));
            H[16 * 66 + row16 * 66 + n * 16 + r16] = f2bf(silu_(aG[n][j] + g1b[n]));
        }
    }

    f32x4 oC[4] = {}, oG[4] = {};
    #pragma unroll
    for (int kt = 0; kt < 2; ++kt){
        s16x8 hc = *(const s16x8*)&H[r16 * 66 + kt * 32 + grp * 8];
        s16x8 hg = *(const s16x8*)&H[16 * 66 + r16 * 66 + kt * 32 + grp * 8];
        #pragma unroll
        for (int n = 0; n < 4; ++n){
            s16x8 bc = *(const s16x8*)&w2cT[(n * 16 + r16) * 64 + kt * 32 + grp * 8];
            s16x8 bg = *(const s16x8*)&w2gT[(n * 16 + r16) * 64 + kt * 32 + grp * 8];
            oC[n] = MFMA16(hc, bc, oC[n]);
            oG[n] = MFMA16(hg, bg, oG[n]);
        }
    }
    #pragma unroll
    for (int n = 0; n < 4; ++n){
        #pragma unroll
        for (int j = 0; j < 4; ++j){
            int row16 = grp * 4 + j;
            float v = silu_(oC[n][j] + c2b[n]) * sigm_(oG[n][j] + g2b[n]);
            v *= bf2f(bwagBf[(size_t)ubw[j] * 64 + n * 16 + r16]);
            H[32 * 66 + row16 * 66 + n * 16 + r16] = f2bf(v);
        }
    }

    f32x4 oD[4] = {};
    #pragma unroll
    for (int kt = 0; kt < 2; ++kt){
        s16x8 a = *(const s16x8*)&H[32 * 66 + r16 * 66 + kt * 32 + grp * 8];
        #pragma unroll
        for (int n = 0; n < 4; ++n){
            s16x8 bo = *(const s16x8*)&woT[(n * 16 + r16) * 64 + kt * 32 + grp * 8];
            oD[n] = MFMA16(a, bo, oD[n]);
        }
    }
    #pragma unroll
    for (int n = 0; n < 4; ++n){
        #pragma unroll
        for (int j = 0; j < 4; ++j){
            int r = wrow0 + grp * 4 + j;
            upd[(size_t)r * 64 + n * 16 + r16] = f2bf(oD[n][j]);   // dense in sorted space
        }
    }
}

// ---------------- bond conv: barrier-free, wave owns 16 rows
__global__ __launch_bounds__(256, 4) void k_bond_conv(
    const unsigned short* __restrict__ atomBf, const unsigned short* __restrict__ bondBf,
    const unsigned short* __restrict__ angleBf, const unsigned short* __restrict__ bwbgBf,
    const int* __restrict__ bga, const int* __restrict__ bgb,
    const int* __restrict__ idxB,
    const unsigned short* __restrict__ w1cT, const unsigned short* __restrict__ w1gT,
    const unsigned short* __restrict__ w2cT, const unsigned short* __restrict__ w2gT,
    const unsigned short* __restrict__ woT,
    const float* __restrict__ cb1, const float* __restrict__ cb2,
    const float* __restrict__ gb1, const float* __restrict__ gb2,
    unsigned short* __restrict__ upd)
{
    __shared__ unsigned short ldsA[64 * 264];   // per-wave 16-row regions; H/V overlay after L1
    const int tid   = threadIdx.x;
    const int lane  = tid & 63, wid = tid >> 6;
    const int r16   = lane & 15, grp = lane >> 4;
    const int lane8 = lane & 7;
    const int wrow0 = blockIdx.x * 64 + wid * 16;

    #pragma unroll
    for (int p = 0; p < 8; ++p){
        int cc = p * 8 + (lane >> 3);
        int row16 = cc & 15, q = cc >> 4;
        int a = idxB[wrow0 + row16];
        const unsigned short* src;
        if (q == 0)      src = bondBf  + (size_t)bgb[2 * a] * 64;
        else if (q == 1) src = bondBf  + (size_t)bgb[2 * a + 1] * 64;
        else if (q == 2) src = angleBf + (size_t)a * 64;
        else             src = atomBf  + (size_t)bga[a] * 64;
        *(u32x4*)&ldsA[(wid * 16 + row16) * 264 + q * 64 + lane8 * 8] =
            *(const u32x4*)(src + lane8 * 8);
    }
    int ubw[4];
    #pragma unroll
    for (int j = 0; j < 4; ++j) ubw[j] = bgb[2 * idxB[wrow0 + grp * 4 + j]];

    float c1b[4], g1b[4], c2b[4], g2b[4];
    #pragma unroll
    for (int n = 0; n < 4; ++n){
        c1b[n] = cb1[n * 16 + r16]; g1b[n] = gb1[n * 16 + r16];
        c2b[n] = cb2[n * 16 + r16]; g2b[n] = gb2[n * 16 + r16];
    }

    const unsigned short* Arow = ldsA + (wid * 16 + r16) * 264;
    f32x4 aC[4] = {}, aG[4] = {};
    #pragma unroll
    for (int kt = 0; kt < 8; ++kt){
        s16x8 a = *(const s16x8*)&Arow[kt * 32 + grp * 8];
        #pragma unroll
        for (int n = 0; n < 4; ++n){
            s16x8 bc = *(const s16x8*)&w1cT[(n * 16 + r16) * 256 + kt * 32 + grp * 8];
            s16x8 bg = *(const s16x8*)&w1gT[(n * 16 + r16) * 256 + kt * 32 + grp * 8];
            aC[n] = MFMA16(a, bc, aC[n]);
            aG[n] = MFMA16(a, bg, aG[n]);
        }
    }

    unsigned short* H = ldsA + wid * 16 * 264;   // stride 74; HC:0 HG:16*74 V:32*74
    #pragma unroll
    for (int n = 0; n < 4; ++n){
        #pragma unroll
        for (int j = 0; j < 4; ++j){
            int row16 = grp * 4 + j;
            H[row16 * 74 + n * 16 + r16]           = f2bf(silu_(aC[n][j] + c1b[n]));
            H[16 * 74 + row16 * 74 + n * 16 + r16] = f2bf(silu_(aG[n][j] + g1b[n]));
        }
    }

    f32x4 oC[4] = {}, oG[4] = {};
    #pragma unroll
    for (int kt = 0; kt < 2; ++kt){
        s16x8 hc = *(const s16x8*)&H[r16 * 74 + kt * 32 + grp * 8];
        s16x8 hg = *(const s16x8*)&H[16 * 74 + r16 * 74 + kt * 32 + grp * 8];
        #pragma unroll
        for (int n = 0; n < 4; ++n){
            s16x8 bc = *(const s16x8*)&w2cT[(n * 16 + r16) * 64 + kt * 32 + grp * 8];
            s16x8 bg = *(const s16x8*)&w2gT[(n * 16 + r16) * 64 + kt * 32 + grp * 8];
            oC[n] = MFMA16(hc, bc, oC[n]);
            oG[n] = MFMA16(hg, bg, oG[n]);
        }
    }
    #pragma unroll
    for (int n = 0; n < 4; ++n){
        #pragma unroll
        for (int j = 0; j < 4; ++j){
            int row16 = grp * 4 + j;
            float v = silu_(oC[n][j] + c2b[n]) * sigm_(oG[n][j] + g2b[n]);
            v *= bf2f(bwbgBf[(size_t)ubw[j] * 64 + n * 16 + r16]);
            H[32 * 74 + row16 * 74 + n * 16 + r16] = f2bf(v);
        }
    }

    f32x4 oD[4] = {};
    #pragma unroll
    for (int kt = 0; kt < 2; ++kt){
        s16x8 a = *(const s16x8*)&H[32 * 74 + r16 * 74 + kt * 32 + grp * 8];
        #pragma unroll
        for (int n = 0; n < 4; ++n){
            s16x8 bo = *(const s16x8*)&woT[(n * 16 + r16) * 64 + kt * 32 + grp * 8];
            oD[n] = MFMA16(a, bo, oD[n]);
        }
    }
    #pragma unroll
    for (int n = 0; n < 4; ++n){
        #pragma unroll
        for (int j = 0; j < 4; ++j){
            int r = wrow0 + grp * 4 + j;
            upd[(size_t)r * 64 + n * 16 + r16] = f2bf(oD[n][j]);
        }
    }
}

// ---------------- angle update: barrier-free, wave owns 16 rows
__global__ __launch_bounds__(256, 4) void k_angle(
    const unsigned short* __restrict__ atomBf, const unsigned short* __restrict__ bondBf,
    unsigned short* __restrict__ angleBf,
    const int* __restrict__ bga, const int* __restrict__ bgb,
    const int* __restrict__ idxB,
    const unsigned short* __restrict__ wcT, const unsigned short* __restrict__ wgT,
    const float* __restrict__ cb, const float* __restrict__ gb)
{
    __shared__ unsigned short ldsA[64 * 264];
    const int tid   = threadIdx.x;
    const int lane  = tid & 63, wid = tid >> 6;
    const int r16   = lane & 15, grp = lane >> 4;
    const int lane8 = lane & 7;
    const int wrow0 = blockIdx.x * 64 + wid * 16;

    #pragma unroll
    for (int p = 0; p < 8; ++p){
        int cc = p * 8 + (lane >> 3);
        int row16 = cc & 15, q = cc >> 4;
        int a = idxB[wrow0 + row16];
        const unsigned short* src;
        if (q == 0)      src = bondBf  + (size_t)bgb[2 * a] * 64;
        else if (q == 1) src = bondBf  + (size_t)bgb[2 * a + 1] * 64;
        else if (q == 2) src = angleBf + (size_t)a * 64;
        else             src = atomBf  + (size_t)bga[a] * 64;
        *(u32x4*)&ldsA[(wid * 16 + row16) * 264 + q * 64 + lane8 * 8] =
            *(const u32x4*)(src + lane8 * 8);
    }
    int aid[4];
    #pragma unroll
    for (int j = 0; j < 4; ++j) aid[j] = idxB[wrow0 + grp * 4 + j];

    float cbv[4], gbv[4];
    #pragma unroll
    for (int n = 0; n < 4; ++n){ cbv[n] = cb[n * 16 + r16]; gbv[n] = gb[n * 16 + r16]; }

    const unsigned short* Arow = ldsA + (wid * 16 + r16) * 264;
    f32x4 aC[4] = {}, aG[4] = {};
    #pragma unroll
    for (int kt = 0; kt < 8; ++kt){
        s16x8 a = *(const s16x8*)&Arow[kt * 32 + grp * 8];
        #pragma unroll
        for (int n = 0; n < 4; ++n){
            s16x8 bc = *(const s16x8*)&wcT[(n * 16 + r16) * 256 + kt * 32 + grp * 8];
            s16x8 bg = *(const s16x8*)&wgT[(n * 16 + r16) * 256 + kt * 32 + grp * 8];
            aC[n] = MFMA16(a, bc, aC[n]);
            aG[n] = MFMA16(a, bg, aG[n]);
        }
    }
    #pragma unroll
    for (int n = 0; n < 4; ++n){
        #pragma unroll
        for (int j = 0; j < 4; ++j){
            int row16 = grp * 4 + j;
            float oldv = bf2f(ldsA[(wid * 16 + row16) * 264 + 128 + n * 16 + r16]);
            float v = silu_(aC[n][j] + cbv[n]) * sigm_(aG[n][j] + gbv[n]);
            angleBf[(size_t)aid[j] * 64 + n * 16 + r16] = f2bf(oldv + v);
        }
    }
}

// ---------------- readout MLP + segmented sum (wave per atom row)
__global__ __launch_bounds__(256) void k_readout(
    const unsigned short* __restrict__ atomBf, const int* __restrict__ owners,
    const float* __restrict__ w1, const float* __restrict__ b1,
    const float* __restrict__ w2, const float* __restrict__ b2,
    const float* __restrict__ w3, const float* __restrict__ b3,
    float* __restrict__ esum, float* __restrict__ cnt)
{
    int gid  = blockIdx.x * 256 + threadIdx.x;
    int n    = gid >> 6;
    int lane = threadIdx.x & 63;
    float a = bf2f(atomBf[n * 64 + lane]);
    float acc = b1[lane];
    #pragma unroll
    for (int k = 0; k < 64; ++k) acc += __shfl(a, k) * w1[k * 64 + lane];
    float h = silu_(acc);
    acc = b2[lane];
    #pragma unroll
    for (int k = 0; k < 64; ++k) acc += __shfl(h, k) * w2[k * 64 + lane];
    h = silu_(acc);
    float p = h * w3[lane];
    #pragma unroll
    for (int off = 32; off > 0; off >>= 1) p += __shfl_xor(p, off);
    if (lane == 0){
        atomicAdd(&esum[owners[n]], p + b3[0]);
        atomicAdd(&cnt[owners[n]], 1.0f);
    }
}

__global__ void k_final(const float* __restrict__ esum, const float* __restrict__ cnt,
                        float* __restrict__ out){
    int i = threadIdx.x;
    if (i < 128) out[i] = esum[i] / fmaxf(cnt[i], 1.0f);
}

extern "C" void kernel_launch(void* const* d_in, const int* in_sizes, int n_in,
                              void* d_out, int out_size, void* d_ws, size_t ws_size,
                              hipStream_t stream)
{
    (void)in_sizes; (void)n_in; (void)out_size; (void)ws_size;
    const int N_ATOMS = 8192, N_UND = 65536, N_DIR = 131072, N_ANG = 262144;

    const int*   atomic_numbers = (const int*)  d_in[0];
    const float* bb_ag  = (const float*)d_in[1];
    const float* bb_bg  = (const float*)d_in[2];
    const float* ang_b  = (const float*)d_in[3];
    const int*   agraph = (const int*)  d_in[4];
    const int*   d2u    = (const int*)  d_in[5];
    const int*   bga    = (const int*)  d_in[6];
    const int*   bgb    = (const int*)  d_in[7];
    const int*   owners = (const int*)  d_in[8];
    const float* emb    = (const float*)d_in[9];
    const float* Wb     = (const float*)d_in[10];
    const float* Wa     = (const float*)d_in[11];
    const float* Wbwag  = (const float*)d_in[12];
    const float* Wbwbg  = (const float*)d_in[13];
    const float* ac_cw1 = (const float*)d_in[14];
    const float* ac_cb1 = (const float*)d_in[15];
    const float* ac_cw2 = (const float*)d_in[16];
    const float* ac_cb2 = (const float*)d_in[17];
    const float* ac_gw1 = (const float*)d_in[18];
    const float* ac_gb1 = (const float*)d_in[19];
    const float* ac_gw2 = (const float*)d_in[20];
    const float* ac_gb2 = (const float*)d_in[21];
    const float* ac_out = (const float*)d_in[22];
    const float* bc_cw1 = (const float*)d_in[23];
    const float* bc_cb1 = (const float*)d_in[24];
    const float* bc_cw2 = (const float*)d_in[25];
    const float* bc_cb2 = (const float*)d_in[26];
    const float* bc_gw1 = (const float*)d_in[27];
    const float* bc_gb1 = (const float*)d_in[28];
    const float* bc_gw2 = (const float*)d_in[29];
    const float* bc_gb2 = (const float*)d_in[30];
    const float* bc_out = (const float*)d_in[31];
    const float* an_cw  = (const float*)d_in[32];
    const float* an_cb  = (const float*)d_in[33];
    const float* an_gw  = (const float*)d_in[34];
    const float* an_gb  = (const float*)d_in[35];
    const float* ro_w1  = (const float*)d_in[36];
    const float* ro_b1  = (const float*)d_in[37];
    const float* ro_w2  = (const float*)d_in[38];
    const float* ro_b2  = (const float*)d_in[39];
    const float* ro_w3  = (const float*)d_in[40];
    const float* ro_b3  = (const float*)d_in[41];

    char* ws = (char*)d_ws;
    size_t off = 0;
    auto alloc = [&](size_t bytes) -> void* {
        void* p = ws + off;
        off = (off + bytes + 255) & ~(size_t)255;
        return p;
    };
    unsigned short* atomBf  = (unsigned short*)alloc((size_t)N_ATOMS * 64 * 2);
    unsigned short* bondBf  = (unsigned short*)alloc((size_t)N_UND   * 64 * 2);
    unsigned short* angleBf = (unsigned short*)alloc((size_t)N_ANG   * 64 * 2);
    unsigned short* bwagBf  = (unsigned short*)alloc((size_t)N_UND   * 64 * 2);
    unsigned short* bwbgBf  = (unsigned short*)alloc((size_t)N_UND   * 64 * 2);
    unsigned short* updBuf  = (unsigned short*)alloc((size_t)N_ANG   * 64 * 2);
    float* esum   = (float*)alloc(128 * 4);
    float* cnt    = (float*)alloc(128 * 4);
    int* offsA = (int*)alloc((N_ATOMS + 1) * 4);
    int* curA  = (int*)alloc(N_ATOMS * 4);
    int* idxA  = (int*)alloc((size_t)N_DIR * 4);
    int* offsB = (int*)alloc((N_UND + 1) * 4);
    int* curB  = (int*)alloc(N_UND * 4);
    int* idxB  = (int*)alloc((size_t)N_ANG * 4);
    int* bsum  = (int*)alloc(256 * 4);
    int* bbase = (int*)alloc(256 * 4);
    unsigned short* acw1cT = (unsigned short*)alloc((size_t)4 * 64 * 192 * 2);
    unsigned short* acw1gT = (unsigned short*)alloc((size_t)4 * 64 * 192 * 2);
    unsigned short* acw2cT = (unsigned short*)alloc((size_t)4 * 64 * 64 * 2);
    unsigned short* acw2gT = (unsigned short*)alloc((size_t)4 * 64 * 64 * 2);
    unsigned short* acoT   = (unsigned short*)alloc((size_t)4 * 64 * 64 * 2);
    unsigned short* bcw1cT = (unsigned short*)alloc((size_t)3 * 64 * 256 * 2);
    unsigned short* bcw1gT = (unsigned short*)alloc((size_t)3 * 64 * 256 * 2);
    unsigned short* bcw2cT = (unsigned short*)alloc((size_t)3 * 64 * 64 * 2);
    unsigned short* bcw2gT = (unsigned short*)alloc((size_t)3 * 64 * 64 * 2);
    unsigned short* bcoT   = (unsigned short*)alloc((size_t)3 * 64 * 64 * 2);
    unsigned short* anwcT  = (unsigned short*)alloc((size_t)3 * 64 * 256 * 2);
    unsigned short* anwgT  = (unsigned short*)alloc((size_t)3 * 64 * 256 * 2);

    auto tc = [&](const float* src, unsigned short* dst, int B, int K){
        int total = B * K * 64;
        k_transconv<<<(total + 255) / 256, 256, 0, stream>>>(src, dst, K, total);
    };
    tc(ac_cw1, acw1cT, 4, 192);  tc(ac_gw1, acw1gT, 4, 192);
    tc(ac_cw2, acw2cT, 4, 64);   tc(ac_gw2, acw2gT, 4, 64);
    tc(ac_out, acoT,   4, 64);
    tc(bc_cw1, bcw1cT, 3, 256);  tc(bc_gw1, bcw1gT, 3, 256);
    tc(bc_cw2, bcw2cT, 3, 64);   tc(bc_gw2, bcw2gT, 3, 64);
    tc(bc_out, bcoT,   3, 64);
    tc(an_cw,  anwcT,  3, 256);  tc(an_gw,  anwgT,  3, 256);

    k_embed<<<N_ATOMS * 64 / 256, 256, 0, stream>>>(emb, atomic_numbers, atomBf);
    k_smallmm<<<N_UND * 64 / 256, 256, 0, stream>>>(bb_ag, Wb,    bondBf);
    k_smallmm<<<N_ANG * 64 / 256, 256, 0, stream>>>(ang_b, Wa,    angleBf);
    k_smallmm<<<N_UND * 64 / 256, 256, 0, stream>>>(bb_ag, Wbwag, bwagBf);
    k_smallmm<<<N_UND * 64 / 256, 256, 0, stream>>>(bb_bg, Wbwbg, bwbgBf);

    // CSR build (graph static across iterations), hierarchical scan
    hipMemsetAsync(curA, 0, N_ATOMS * 4, stream);
    k_count<<<(N_DIR + 255) / 256, 256, 0, stream>>>(agraph, 2, N_DIR, curA);
    k_bsum <<<N_ATOMS / 256, 256, 0, stream>>>(curA, bsum);
    k_bscan<<<1, 256, 0, stream>>>(bsum, bbase, N_ATOMS / 256, offsA + N_ATOMS);
    k_offs <<<N_ATOMS / 256, 256, 0, stream>>>(curA, bbase, offsA);
    hipMemsetAsync(curA, 0, N_ATOMS * 4, stream);
    k_fill<<<(N_DIR + 255) / 256, 256, 0, stream>>>(agraph, 2, N_DIR, offsA, curA, idxA);

    hipMemsetAsync(curB, 0, N_UND * 4, stream);
    k_count<<<(N_ANG + 255) / 256, 256, 0, stream>>>(bgb, 2, N_ANG, curB);
    k_bsum <<<N_UND / 256, 256, 0, stream>>>(curB, bsum);
    k_bscan<<<1, 256, 0, stream>>>(bsum, bbase, N_UND / 256, offsB + N_UND);
    k_offs <<<N_UND / 256, 256, 0, stream>>>(curB, bbase, offsB);
    hipMemsetAsync(curB, 0, N_UND * 4, stream);
    k_fill<<<(N_ANG + 255) / 256, 256, 0, stream>>>(bgb, 2, N_ANG, offsB, curB, idxB);

    for (int i = 0; i < 4; ++i){
        k_atom_conv<<<N_DIR / 64, 256, 0, stream>>>(
            atomBf, bondBf, bwagBf, agraph, d2u, idxA,
            acw1cT + (size_t)i * 64 * 192, acw1gT + (size_t)i * 64 * 192,
            acw2cT + (size_t)i * 64 * 64,  acw2gT + (size_t)i * 64 * 64,
            acoT   + (size_t)i * 64 * 64,
            ac_cb1 + i * 64, ac_cb2 + i * 64, ac_gb1 + i * 64, ac_gb2 + i * 64, updBuf);
        k_reduce<<<N_ATOMS * 8 / 256, 256, 0, stream>>>(updBuf, offsA, atomBf, N_ATOMS);
        if (i == 3) break;
        k_bond_conv<<<N_ANG / 64, 256, 0, stream>>>(
            atomBf, bondBf, angleBf, bwbgBf, bga, bgb, idxB,
            bcw1cT + (size_t)i * 64 * 256, bcw1gT + (size_t)i * 64 * 256,
            bcw2cT + (size_t)i * 64 * 64,  bcw2gT + (size_t)i * 64 * 64,
            bcoT   + (size_t)i * 64 * 64,
            bc_cb1 + i * 64, bc_cb2 + i * 64, bc_gb1 + i * 64, bc_gb2 + i * 64, updBuf);
        k_reduce<<<N_UND * 8 / 256, 256, 0, stream>>>(updBuf, offsB, bondBf, N_UND);
        k_angle<<<N_ANG / 64, 256, 0, stream>>>(
            atomBf, bondBf, angleBf, bga, bgb, idxB,
            anwcT + (size_t)i * 64 * 256, anwgT + (size_t)i * 64 * 256,
            an_cb + i * 64, an_gb + i * 64);
    }

    hipMemsetAsync(esum, 0, 128 * 4, stream);
    hipMemsetAsync(cnt,  0, 128 * 4, stream);
    k_readout<<<N_ATOMS * 64 / 256, 256, 0, stream>>>(
        atomBf, owners, ro_w1, ro_b1, ro_w2, ro_b2, ro_w3, ro_b3, esum, cnt);
    k_final<<<1, 128, 0, stream>>>(esum, cnt, (float*)d_out);
}

// Round 10
// 870.898 us; speedup vs baseline: 1.7007x; 1.7007x over previous
//
#include <hip/hip_runtime.h>
#include <hip/hip_bf16.h>

typedef float f32x4 __attribute__((ext_vector_type(4)));
typedef short s16x8 __attribute__((ext_vector_type(8)));
typedef unsigned int u32x4 __attribute__((ext_vector_type(4)));

#define DEV static __device__ __forceinline__

DEV unsigned short f2bf(float x){
    unsigned u = __builtin_bit_cast(unsigned, x);
    u += 0x7FFFu + ((u >> 16) & 1u);
    return (unsigned short)(u >> 16);
}
DEV float bf2f(unsigned short h){
    unsigned u = ((unsigned)h) << 16;
    return __builtin_bit_cast(float, u);
}
DEV float sigm_(float x){ return __builtin_amdgcn_rcpf(1.0f + __expf(-x)); }
DEV float silu_(float x){ return x * sigm_(x); }

// XCD-aware swizzle: consecutive work chunks land on the same XCD's L2.
// Requires gridDim.x % 8 == 0 (all conv grids are 2048 or 4096).
DEV int xcd_swz(){
    int bid = blockIdx.x, nwg = gridDim.x;
    return (bid & 7) * (nwg >> 3) + (bid >> 3);
}

// ---------------- weight transpose + convert:  src [B][K][64] f32 -> dst [B][64][K] bf16
__global__ __launch_bounds__(256) void k_transconv(const float* __restrict__ src,
                                                   unsigned short* __restrict__ dst,
                                                   int K, int total){
    int gid = blockIdx.x * 256 + threadIdx.x;
    if (gid >= total) return;
    int kn  = K * 64;
    int b   = gid / kn;
    int rem = gid - b * kn;
    int k   = rem >> 6, n = rem & 63;
    dst[b * kn + n * K + k] = f2bf(src[gid]);
}

// ---------------- atom embedding gather
__global__ __launch_bounds__(256) void k_embed(const float* __restrict__ emb,
                                               const int* __restrict__ z,
                                               unsigned short* __restrict__ out){
    int gid = blockIdx.x * 256 + threadIdx.x;
    int n = gid >> 6, f = gid & 63;
    out[gid] = f2bf(emb[z[n] * 64 + f]);
}

// ---------------- bases[rows][9] @ W[9][64] -> bf16 out[rows][64]
__global__ __launch_bounds__(256) void k_smallmm(const float* __restrict__ bases,
                                                 const float* __restrict__ W,
                                                 unsigned short* __restrict__ out){
    int gid = blockIdx.x * 256 + threadIdx.x;
    int r = gid >> 6, f = gid & 63;
    const float* b = bases + r * 9;
    float acc = 0.f;
    #pragma unroll
    for (int k = 0; k < 9; ++k) acc += b[k] * W[k * 64 + f];
    out[gid] = f2bf(acc);
}

// ---------------- CSR build helpers
__global__ void k_count(const int* __restrict__ dst, int stride, int n, int* __restrict__ cnt){
    int i = blockIdx.x * 256 + threadIdx.x;
    if (i < n) atomicAdd(&cnt[dst[(size_t)i * stride]], 1);
}

__global__ __launch_bounds__(256) void k_bsum(const int* __restrict__ cnt,
                                              int* __restrict__ bsum){
    int i = blockIdx.x * 256 + threadIdx.x;
    int v = cnt[i];
    #pragma unroll
    for (int off = 32; off > 0; off >>= 1) v += __shfl_down(v, off);
    __shared__ int ws[4];
    if ((threadIdx.x & 63) == 0) ws[threadIdx.x >> 6] = v;
    __syncthreads();
    if (threadIdx.x == 0) bsum[blockIdx.x] = ws[0] + ws[1] + ws[2] + ws[3];
}

__global__ __launch_bounds__(256) void k_bscan(const int* __restrict__ bsum,
                                               int* __restrict__ bbase, int nb,
                                               int* __restrict__ total_out){
    __shared__ int sh[256];
    int t = threadIdx.x;
    int v = (t < nb) ? bsum[t] : 0;
    sh[t] = v;
    __syncthreads();
    for (int d = 1; d < 256; d <<= 1){
        int u = (t >= d) ? sh[t - d] : 0;
        __syncthreads();
        sh[t] += u;
        __syncthreads();
    }
    if (t < nb) bbase[t] = sh[t] - v;
    if (t == nb - 1) *total_out = sh[t];
}

__global__ __launch_bounds__(256) void k_offs(const int* __restrict__ cnt,
                                              const int* __restrict__ bbase,
                                              int* __restrict__ offs){
    __shared__ int sh[256];
    int t = threadIdx.x;
    int i = blockIdx.x * 256 + t;
    int v = cnt[i];
    sh[t] = v;
    __syncthreads();
    for (int d = 1; d < 256; d <<= 1){
        int u = (t >= d) ? sh[t - d] : 0;
        __syncthreads();
        sh[t] += u;
        __syncthreads();
    }
    offs[i] = bbase[blockIdx.x] + sh[t] - v;
}

__global__ void k_fill(const int* __restrict__ dst, int stride, int n,
                       const int* __restrict__ offs, int* __restrict__ cur,
                       int* __restrict__ idx){
    int i = blockIdx.x * 256 + threadIdx.x;
    if (i < n){
        int d = dst[(size_t)i * stride];
        int p = offs[d] + atomicAdd(&cur[d], 1);
        idx[p] = i;
    }
}

// ---------------- gather-reduce (contiguous): act[row] += sum_{j in [offs[row],offs[row+1])} upd[j]
__global__ __launch_bounds__(256) void k_reduce(const unsigned short* __restrict__ upd,
                                                const int* __restrict__ offs,
                                                unsigned short* __restrict__ act, int nRows){
    int gid = blockIdx.x * 256 + threadIdx.x;
    int row = gid >> 3;
    if (row >= nRows) return;
    int c8 = (gid & 7) * 8;
    int o = offs[row], e = offs[row + 1];
    float acc[8] = {};
    for (int j = o; j < e; ++j){
        s16x8 v = *(const s16x8*)&upd[(size_t)j * 64 + c8];
        #pragma unroll
        for (int q = 0; q < 8; ++q) acc[q] += bf2f((unsigned short)v[q]);
    }
    s16x8 a = *(s16x8*)&act[(size_t)row * 64 + c8];
    #pragma unroll
    for (int q = 0; q < 8; ++q) a[q] = (short)f2bf(bf2f((unsigned short)a[q]) + acc[q]);
    *(s16x8*)&act[(size_t)row * 64 + c8] = a;
}

#define MFMA16(a,b,c) __builtin_amdgcn_mfma_f32_16x16x32_bf16(a,b,c,0,0,0)

// ---------------- atom conv: edges processed in CSR-sorted order (by center atom)
__global__ __launch_bounds__(256, 4) void k_atom_conv(
    const unsigned short* __restrict__ atomBf, const unsigned short* __restrict__ bondBf,
    const unsigned short* __restrict__ bwagBf,
    const int* __restrict__ agraph, const int* __restrict__ d2u,
    const int* __restrict__ idxA,
    const unsigned short* __restrict__ w1cT, const unsigned short* __restrict__ w1gT,
    const unsigned short* __restrict__ w2cT, const unsigned short* __restrict__ w2gT,
    const unsigned short* __restrict__ woT,
    const float* __restrict__ cb1, const float* __restrict__ cb2,
    const float* __restrict__ gb1, const float* __restrict__ gb2,
    unsigned short* __restrict__ upd)
{
    __shared__ unsigned short lds[14208];   // overlay: ldsA [64][200] | HC,HG,V [64][74]
    __shared__ unsigned short ldsBw[64 * 68];
    __shared__ int ldsSrc[256];
    unsigned short* ldsA  = lds;
    unsigned short* ldsHC = lds;
    unsigned short* ldsHG = lds + 4736;
    unsigned short* ldsV  = lds + 9472;
    const int tid = threadIdx.x;
    const int r0  = xcd_swz() * 64;

    {   // phase 0: source row indices. q blocks: 0=atom[ag0] 1=bond[d2u] 2=atom[ag1] 3=bw[d2u]
        int q = tid >> 6, row = tid & 63;
        int e = idxA[r0 + row];
        int s;
        if (q == 0)      s = agraph[2 * e];
        else if (q == 1) s = d2u[e];
        else if (q == 2) s = agraph[2 * e + 1];
        else             s = d2u[e];
        ldsSrc[tid] = s;
    }
    __syncthreads();
    {   // phase 1: coalesced copies, 8 lanes per 128B row
        const int lane8 = tid & 7;
        #pragma unroll
        for (int p = 0; p < 8; ++p){
            int cc = p * 32 + (tid >> 3);
            int q = cc >> 6, row = cc & 63;
            int s = ldsSrc[cc];
            const unsigned short* buf = (q == 1 || q == 3) ? bondBf : atomBf;
            if (q == 3) buf = bwagBf;
            u32x4 v = *(const u32x4*)(buf + (size_t)s * 64 + lane8 * 8);
            if (q < 3) *(u32x4*)&ldsA[row * 200 + q * 64 + lane8 * 8] = v;
            else       *(u32x4*)&ldsBw[row * 68 + lane8 * 8] = v;
        }
    }
    __syncthreads();

    const int lane = tid & 63;
    const int r16  = lane & 15;
    const int grp  = lane >> 4;
    const int col  = (tid >> 6) * 16 + r16;

    f32x4 aC[4] = {}, aG[4] = {};
    #pragma unroll
    for (int kt = 0; kt < 6; ++kt){
        s16x8 bc = *(const s16x8*)&w1cT[col * 192 + kt * 32 + grp * 8];
        s16x8 bg = *(const s16x8*)&w1gT[col * 192 + kt * 32 + grp * 8];
        #pragma unroll
        for (int mt = 0; mt < 4; ++mt){
            s16x8 a = *(const s16x8*)&ldsA[(mt * 16 + r16) * 200 + kt * 32 + grp * 8];
            aC[mt] = MFMA16(a, bc, aC[mt]);
            aG[mt] = MFMA16(a, bg, aG[mt]);
        }
    }
    __syncthreads();   // ldsA dead; overlay writable

    const float bC1 = cb1[col], bG1 = gb1[col];
    #pragma unroll
    for (int mt = 0; mt < 4; ++mt){
        #pragma unroll
        for (int j = 0; j < 4; ++j){
            int row = mt * 16 + grp * 4 + j;
            ldsHC[row * 74 + col] = f2bf(silu_(aC[mt][j] + bC1));
            ldsHG[row * 74 + col] = f2bf(silu_(aG[mt][j] + bG1));
        }
    }
    __syncthreads();

    f32x4 oC[4] = {}, oG[4] = {};
    #pragma unroll
    for (int kt = 0; kt < 2; ++kt){
        s16x8 bc = *(const s16x8*)&w2cT[col * 64 + kt * 32 + grp * 8];
        s16x8 bg = *(const s16x8*)&w2gT[col * 64 + kt * 32 + grp * 8];
        #pragma unroll
        for (int mt = 0; mt < 4; ++mt){
            s16x8 hc = *(const s16x8*)&ldsHC[(mt * 16 + r16) * 74 + kt * 32 + grp * 8];
            s16x8 hg = *(const s16x8*)&ldsHG[(mt * 16 + r16) * 74 + kt * 32 + grp * 8];
            oC[mt] = MFMA16(hc, bc, oC[mt]);
            oG[mt] = MFMA16(hg, bg, oG[mt]);
        }
    }
    const float bC2 = cb2[col], bG2 = gb2[col];
    #pragma unroll
    for (int mt = 0; mt < 4; ++mt){
        #pragma unroll
        for (int j = 0; j < 4; ++j){
            int row = mt * 16 + grp * 4 + j;
            float v = silu_(oC[mt][j] + bC2) * sigm_(oG[mt][j] + bG2);
            v *= bf2f(ldsBw[row * 68 + col]);
            ldsV[row * 74 + col] = f2bf(v);
        }
    }
    __syncthreads();

    f32x4 oD[4] = {};
    #pragma unroll
    for (int kt = 0; kt < 2; ++kt){
        s16x8 bo = *(const s16x8*)&woT[col * 64 + kt * 32 + grp * 8];
        #pragma unroll
        for (int mt = 0; mt < 4; ++mt){
            s16x8 a = *(const s16x8*)&ldsV[(mt * 16 + r16) * 74 + kt * 32 + grp * 8];
            oD[mt] = MFMA16(a, bo, oD[mt]);
        }
    }
    #pragma unroll
    for (int mt = 0; mt < 4; ++mt){
        #pragma unroll
        for (int j = 0; j < 4; ++j){
            int row = mt * 16 + grp * 4 + j;
            upd[(size_t)(r0 + row) * 64 + col] = f2bf(oD[mt][j]);   // dense in sorted space
        }
    }
}

// ---------------- bond conv: angles processed in CSR-sorted order (by bgi)
__global__ __launch_bounds__(256, 4) void k_bond_conv(
    const unsigned short* __restrict__ atomBf, const unsigned short* __restrict__ bondBf,
    const unsigned short* __restrict__ angleBf, const unsigned short* __restrict__ bwbgBf,
    const int* __restrict__ bga, const int* __restrict__ bgb,
    const int* __restrict__ idxB,
    const unsigned short* __restrict__ w1cT, const unsigned short* __restrict__ w1gT,
    const unsigned short* __restrict__ w2cT, const unsigned short* __restrict__ w2gT,
    const unsigned short* __restrict__ woT,
    const float* __restrict__ cb1, const float* __restrict__ cb2,
    const float* __restrict__ gb1, const float* __restrict__ gb2,
    unsigned short* __restrict__ upd)
{
    __shared__ unsigned short lds[16896];   // overlay: ldsA [64][264] | HC,HG,V [64][74]
    __shared__ int ldsSrc[256];
    unsigned short* ldsA  = lds;
    unsigned short* ldsHC = lds;
    unsigned short* ldsHG = lds + 4736;
    unsigned short* ldsV  = lds + 9472;
    const int tid = threadIdx.x;
    const int r0  = xcd_swz() * 64;

    {   // q blocks: 0=bond[bgi] 1=bond[bgj] 2=angle 3=atom[bga]
        int q = tid >> 6, row = tid & 63;
        int a = idxB[r0 + row];
        int s;
        if (q == 0)      s = bgb[2 * a];
        else if (q == 1) s = bgb[2 * a + 1];
        else if (q == 2) s = a;
        else             s = bga[a];
        ldsSrc[tid] = s;
    }
    __syncthreads();
    {
        const int lane8 = tid & 7;
        #pragma unroll
        for (int p = 0; p < 8; ++p){
            int cc = p * 32 + (tid >> 3);
            int q = cc >> 6, row = cc & 63;
            int s = ldsSrc[cc];
            const unsigned short* buf = (q < 2) ? bondBf : (q == 2 ? angleBf : atomBf);
            u32x4 v = *(const u32x4*)(buf + (size_t)s * 64 + lane8 * 8);
            *(u32x4*)&ldsA[row * 264 + q * 64 + lane8 * 8] = v;
        }
    }
    __syncthreads();

    const int lane = tid & 63;
    const int r16  = lane & 15;
    const int grp  = lane >> 4;
    const int col  = (tid >> 6) * 16 + r16;

    // bw gather (bgi rows, sorted -> cache-friendly), issued early
    unsigned short bwv[16];
    #pragma unroll
    for (int mt = 0; mt < 4; ++mt)
        #pragma unroll
        for (int j = 0; j < 4; ++j)
            bwv[mt * 4 + j] = bwbgBf[(size_t)ldsSrc[mt * 16 + grp * 4 + j] * 64 + col];

    f32x4 aC[4] = {}, aG[4] = {};
    #pragma unroll
    for (int kt = 0; kt < 8; ++kt){
        s16x8 bc = *(const s16x8*)&w1cT[col * 256 + kt * 32 + grp * 8];
        s16x8 bg = *(const s16x8*)&w1gT[col * 256 + kt * 32 + grp * 8];
        #pragma unroll
        for (int mt = 0; mt < 4; ++mt){
            s16x8 a = *(const s16x8*)&ldsA[(mt * 16 + r16) * 264 + kt * 32 + grp * 8];
            aC[mt] = MFMA16(a, bc, aC[mt]);
            aG[mt] = MFMA16(a, bg, aG[mt]);
        }
    }
    __syncthreads();

    const float bC1 = cb1[col], bG1 = gb1[col];
    #pragma unroll
    for (int mt = 0; mt < 4; ++mt){
        #pragma unroll
        for (int j = 0; j < 4; ++j){
            int row = mt * 16 + grp * 4 + j;
            ldsHC[row * 74 + col] = f2bf(silu_(aC[mt][j] + bC1));
            ldsHG[row * 74 + col] = f2bf(silu_(aG[mt][j] + bG1));
        }
    }
    __syncthreads();

    f32x4 oC[4] = {}, oG[4] = {};
    #pragma unroll
    for (int kt = 0; kt < 2; ++kt){
        s16x8 bc = *(const s16x8*)&w2cT[col * 64 + kt * 32 + grp * 8];
        s16x8 bg = *(const s16x8*)&w2gT[col * 64 + kt * 32 + grp * 8];
        #pragma unroll
        for (int mt = 0; mt < 4; ++mt){
            s16x8 hc = *(const s16x8*)&ldsHC[(mt * 16 + r16) * 74 + kt * 32 + grp * 8];
            s16x8 hg = *(const s16x8*)&ldsHG[(mt * 16 + r16) * 74 + kt * 32 + grp * 8];
            oC[mt] = MFMA16(hc, bc, oC[mt]);
            oG[mt] = MFMA16(hg, bg, oG[mt]);
        }
    }
    const float bC2 = cb2[col], bG2 = gb2[col];
    #pragma unroll
    for (int mt = 0; mt < 4; ++mt){
        #pragma unroll
        for (int j = 0; j < 4; ++j){
            int row = mt * 16 + grp * 4 + j;
            float v = silu_(oC[mt][j] + bC2) * sigm_(oG[mt][j] + bG2);
            v *= bf2f(bwv[mt * 4 + j]);
            ldsV[row * 74 + col] = f2bf(v);
        }
    }
    __syncthreads();

    f32x4 oD[4] = {};
    #pragma unroll
    for (int kt = 0; kt < 2; ++kt){
        s16x8 bo = *(const s16x8*)&woT[col * 64 + kt * 32 + grp * 8];
        #pragma unroll
        for (int mt = 0; mt < 4; ++mt){
            s16x8 a = *(const s16x8*)&ldsV[(mt * 16 + r16) * 74 + kt * 32 + grp * 8];
            oD[mt] = MFMA16(a, bo, oD[mt]);
        }
    }
    #pragma unroll
    for (int mt = 0; mt < 4; ++mt){
        #pragma unroll
        for (int j = 0; j < 4; ++j){
            int row = mt * 16 + grp * 4 + j;
            upd[(size_t)(r0 + row) * 64 + col] = f2bf(oD[mt][j]);   // dense in sorted space
        }
    }
}

// ---------------- angle update (sorted by bgi), in-place residual on angleBf
__global__ __launch_bounds__(256, 4) void k_angle(
    const unsigned short* __restrict__ atomBf, const unsigned short* __restrict__ bondBf,
    unsigned short* __restrict__ angleBf,
    const int* __restrict__ bga, const int* __restrict__ bgb,
    const int* __restrict__ idxB,
    const unsigned short* __restrict__ wcT, const unsigned short* __restrict__ wgT,
    const float* __restrict__ cb, const float* __restrict__ gb)
{
    __shared__ unsigned short ldsA[64 * 264];
    __shared__ int ldsSrc[256];
    const int tid = threadIdx.x;
    const int r0  = xcd_swz() * 64;

    {
        int q = tid >> 6, row = tid & 63;
        int a = idxB[r0 + row];
        int s;
        if (q == 0)      s = bgb[2 * a];
        else if (q == 1) s = bgb[2 * a + 1];
        else if (q == 2) s = a;
        else             s = bga[a];
        ldsSrc[tid] = s;
    }
    __syncthreads();
    {
        const int lane8 = tid & 7;
        #pragma unroll
        for (int p = 0; p < 8; ++p){
            int cc = p * 32 + (tid >> 3);
            int q = cc >> 6, row = cc & 63;
            int s = ldsSrc[cc];
            const unsigned short* buf = (q < 2) ? bondBf : (q == 2 ? angleBf : atomBf);
            u32x4 v = *(const u32x4*)(buf + (size_t)s * 64 + lane8 * 8);
            *(u32x4*)&ldsA[row * 264 + q * 64 + lane8 * 8] = v;
        }
    }
    __syncthreads();

    const int lane = tid & 63;
    const int r16  = lane & 15;
    const int grp  = lane >> 4;
    const int col  = (tid >> 6) * 16 + r16;

    f32x4 aC[4] = {}, aG[4] = {};
    #pragma unroll
    for (int kt = 0; kt < 8; ++kt){
        s16x8 bc = *(const s16x8*)&wcT[col * 256 + kt * 32 + grp * 8];
        s16x8 bg = *(const s16x8*)&wgT[col * 256 + kt * 32 + grp * 8];
        #pragma unroll
        for (int mt = 0; mt < 4; ++mt){
            s16x8 a = *(const s16x8*)&ldsA[(mt * 16 + r16) * 264 + kt * 32 + grp * 8];
            aC[mt] = MFMA16(a, bc, aC[mt]);
            aG[mt] = MFMA16(a, bg, aG[mt]);
        }
    }
    const float bC = cb[col], bG = gb[col];
    #pragma unroll
    for (int mt = 0; mt < 4; ++mt){
        #pragma unroll
        for (int j = 0; j < 4; ++j){
            int row = mt * 16 + grp * 4 + j;
            int a = ldsSrc[128 + row];          // sorted angle id (q==2 slot)
            float oldv = bf2f(ldsA[row * 264 + 128 + col]);
            float v = silu_(aC[mt][j] + bC) * sigm_(aG[mt][j] + bG);
            angleBf[(size_t)a * 64 + col] = f2bf(oldv + v);
        }
    }
}

// ---------------- readout MLP + segmented sum (wave per atom row)
__global__ __launch_bounds__(256) void k_readout(
    const unsigned short* __restrict__ atomBf, const int* __restrict__ owners,
    const float* __restrict__ w1, const float* __restrict__ b1,
    const float* __restrict__ w2, const float* __restrict__ b2,
    const float* __restrict__ w3, const float* __restrict__ b3,
    float* __restrict__ esum, float* __restrict__ cnt)
{
    int gid  = blockIdx.x * 256 + threadIdx.x;
    int n    = gid >> 6;
    int lane = threadIdx.x & 63;
    float a = bf2f(atomBf[n * 64 + lane]);
    float acc = b1[lane];
    #pragma unroll
    for (int k = 0; k < 64; ++k) acc += __shfl(a, k) * w1[k * 64 + lane];
    float h = silu_(acc);
    acc = b2[lane];
    #pragma unroll
    for (int k = 0; k < 64; ++k) acc += __shfl(h, k) * w2[k * 64 + lane];
    h = silu_(acc);
    float p = h * w3[lane];
    #pragma unroll
    for (int off = 32; off > 0; off >>= 1) p += __shfl_xor(p, off);
    if (lane == 0){
        atomicAdd(&esum[owners[n]], p + b3[0]);
        atomicAdd(&cnt[owners[n]], 1.0f);
    }
}

__global__ void k_final(const float* __restrict__ esum, const float* __restrict__ cnt,
                        float* __restrict__ out){
    int i = threadIdx.x;
    if (i < 128) out[i] = esum[i] / fmaxf(cnt[i], 1.0f);
}

extern "C" void kernel_launch(void* const* d_in, const int* in_sizes, int n_in,
                              void* d_out, int out_size, void* d_ws, size_t ws_size,
                              hipStream_t stream)
{
    (void)in_sizes; (void)n_in; (void)out_size; (void)ws_size;
    const int N_ATOMS = 8192, N_UND = 65536, N_DIR = 131072, N_ANG = 262144;

    const int*   atomic_numbers = (const int*)  d_in[0];
    const float* bb_ag  = (const float*)d_in[1];
    const float* bb_bg  = (const float*)d_in[2];
    const float* ang_b  = (const float*)d_in[3];
    const int*   agraph = (const int*)  d_in[4];
    const int*   d2u    = (const int*)  d_in[5];
    const int*   bga    = (const int*)  d_in[6];
    const int*   bgb    = (const int*)  d_in[7];
    const int*   owners = (const int*)  d_in[8];
    const float* emb    = (const float*)d_in[9];
    const float* Wb     = (const float*)d_in[10];
    const float* Wa     = (const float*)d_in[11];
    const float* Wbwag  = (const float*)d_in[12];
    const float* Wbwbg  = (const float*)d_in[13];
    const float* ac_cw1 = (const float*)d_in[14];
    const float* ac_cb1 = (const float*)d_in[15];
    const float* ac_cw2 = (const float*)d_in[16];
    const float* ac_cb2 = (const float*)d_in[17];
    const float* ac_gw1 = (const float*)d_in[18];
    const float* ac_gb1 = (const float*)d_in[19];
    const float* ac_gw2 = (const float*)d_in[20];
    const float* ac_gb2 = (const float*)d_in[21];
    const float* ac_out = (const float*)d_in[22];
    const float* bc_cw1 = (const float*)d_in[23];
    const float* bc_cb1 = (const float*)d_in[24];
    const float* bc_cw2 = (const float*)d_in[25];
    const float* bc_cb2 = (const float*)d_in[26];
    const float* bc_gw1 = (const float*)d_in[27];
    const float* bc_gb1 = (const float*)d_in[28];
    const float* bc_gw2 = (const float*)d_in[29];
    const float* bc_gb2 = (const float*)d_in[30];
    const float* bc_out = (const float*)d_in[31];
    const float* an_cw  = (const float*)d_in[32];
    const float* an_cb  = (const float*)d_in[33];
    const float* an_gw  = (const float*)d_in[34];
    const float* an_gb  = (const float*)d_in[35];
    const float* ro_w1  = (const float*)d_in[36];
    const float* ro_b1  = (const float*)d_in[37];
    const float* ro_w2  = (const float*)d_in[38];
    const float* ro_b2  = (const float*)d_in[39];
    const float* ro_w3  = (const float*)d_in[40];
    const float* ro_b3  = (const float*)d_in[41];

    char* ws = (char*)d_ws;
    size_t off = 0;
    auto alloc = [&](size_t bytes) -> void* {
        void* p = ws + off;
        off = (off + bytes + 255) & ~(size_t)255;
        return p;
    };
    unsigned short* atomBf  = (unsigned short*)alloc((size_t)N_ATOMS * 64 * 2);
    unsigned short* bondBf  = (unsigned short*)alloc((size_t)N_UND   * 64 * 2);
    unsigned short* angleBf = (unsigned short*)alloc((size_t)N_ANG   * 64 * 2);
    unsigned short* bwagBf  = (unsigned short*)alloc((size_t)N_UND   * 64 * 2);
    unsigned short* bwbgBf  = (unsigned short*)alloc((size_t)N_UND   * 64 * 2);
    unsigned short* updBuf  = (unsigned short*)alloc((size_t)N_ANG   * 64 * 2);
    float* esum   = (float*)alloc(128 * 4);
    float* cnt    = (float*)alloc(128 * 4);
    int* offsA = (int*)alloc((N_ATOMS + 1) * 4);
    int* curA  = (int*)alloc(N_ATOMS * 4);
    int* idxA  = (int*)alloc((size_t)N_DIR * 4);
    int* offsB = (int*)alloc((N_UND + 1) * 4);
    int* curB  = (int*)alloc(N_UND * 4);
    int* idxB  = (int*)alloc((size_t)N_ANG * 4);
    int* bsum  = (int*)alloc(256 * 4);
    int* bbase = (int*)alloc(256 * 4);
    unsigned short* acw1cT = (unsigned short*)alloc((size_t)4 * 64 * 192 * 2);
    unsigned short* acw1gT = (unsigned short*)alloc((size_t)4 * 64 * 192 * 2);
    unsigned short* acw2cT = (unsigned short*)alloc((size_t)4 * 64 * 64 * 2);
    unsigned short* acw2gT = (unsigned short*)alloc((size_t)4 * 64 * 64 * 2);
    unsigned short* acoT   = (unsigned short*)alloc((size_t)4 * 64 * 64 * 2);
    unsigned short* bcw1cT = (unsigned short*)alloc((size_t)3 * 64 * 256 * 2);
    unsigned short* bcw1gT = (unsigned short*)alloc((size_t)3 * 64 * 256 * 2);
    unsigned short* bcw2cT = (unsigned short*)alloc((size_t)3 * 64 * 64 * 2);
    unsigned short* bcw2gT = (unsigned short*)alloc((size_t)3 * 64 * 64 * 2);
    unsigned short* bcoT   = (unsigned short*)alloc((size_t)3 * 64 * 64 * 2);
    unsigned short* anwcT  = (unsigned short*)alloc((size_t)3 * 64 * 256 * 2);
    unsigned short* anwgT  = (unsigned short*)alloc((size_t)3 * 64 * 256 * 2);

    auto tc = [&](const float* src, unsigned short* dst, int B, int K){
        int total = B * K * 64;
        k_transconv<<<(total + 255) / 256, 256, 0, stream>>>(src, dst, K, total);
    };
    tc(ac_cw1, acw1cT, 4, 192);  tc(ac_gw1, acw1gT, 4, 192);
    tc(ac_cw2, acw2cT, 4, 64);   tc(ac_gw2, acw2gT, 4, 64);
    tc(ac_out, acoT,   4, 64);
    tc(bc_cw1, bcw1cT, 3, 256);  tc(bc_gw1, bcw1gT, 3, 256);
    tc(bc_cw2, bcw2cT, 3, 64);   tc(bc_gw2, bcw2gT, 3, 64);
    tc(bc_out, bcoT,   3, 64);
    tc(an_cw,  anwcT,  3, 256);  tc(an_gw,  anwgT,  3, 256);

    k_embed<<<N_ATOMS * 64 / 256, 256, 0, stream>>>(emb, atomic_numbers, atomBf);
    k_smallmm<<<N_UND * 64 / 256, 256, 0, stream>>>(bb_ag, Wb,    bondBf);
    k_smallmm<<<N_ANG * 64 / 256, 256, 0, stream>>>(ang_b, Wa,    angleBf);
    k_smallmm<<<N_UND * 64 / 256, 256, 0, stream>>>(bb_ag, Wbwag, bwagBf);
    k_smallmm<<<N_UND * 64 / 256, 256, 0, stream>>>(bb_bg, Wbwbg, bwbgBf);

    // CSR build (graph static across iterations), hierarchical scan
    hipMemsetAsync(curA, 0, N_ATOMS * 4, stream);
    k_count<<<(N_DIR + 255) / 256, 256, 0, stream>>>(agraph, 2, N_DIR, curA);
    k_bsum <<<N_ATOMS / 256, 256, 0, stream>>>(curA, bsum);
    k_bscan<<<1, 256, 0, stream>>>(bsum, bbase, N_ATOMS / 256, offsA + N_ATOMS);
    k_offs <<<N_ATOMS / 256, 256, 0, stream>>>(curA, bbase, offsA);
    hipMemsetAsync(curA, 0, N_ATOMS * 4, stream);
    k_fill<<<(N_DIR + 255) / 256, 256, 0, stream>>>(agraph, 2, N_DIR, offsA, curA, idxA);

    hipMemsetAsync(curB, 0, N_UND * 4, stream);
    k_count<<<(N_ANG + 255) / 256, 256, 0, stream>>>(bgb, 2, N_ANG, curB);
    k_bsum <<<N_UND / 256, 256, 0, stream>>>(curB, bsum);
    k_bscan<<<1, 256, 0, stream>>>(bsum, bbase, N_UND / 256, offsB + N_UND);
    k_offs <<<N_UND / 256, 256, 0, stream>>>(curB, bbase, offsB);
    hipMemsetAsync(curB, 0, N_UND * 4, stream);
    k_fill<<<(N_ANG + 255) / 256, 256, 0, stream>>>(bgb, 2, N_ANG, offsB, curB, idxB);

    for (int i = 0; i < 4; ++i){
        k_atom_conv<<<N_DIR / 64, 256, 0, stream>>>(
            atomBf, bondBf, bwagBf, agraph, d2u, idxA,
            acw1cT + (size_t)i * 64 * 192, acw1gT + (size_t)i * 64 * 192,
            acw2cT + (size_t)i * 64 * 64,  acw2gT + (size_t)i * 64 * 64,
            acoT   + (size_t)i * 64 * 64,
            ac_cb1 + i * 64, ac_cb2 + i * 64, ac_gb1 + i * 64, ac_gb2 + i * 64, updBuf);
        k_reduce<<<N_ATOMS * 8 / 256, 256, 0, stream>>>(updBuf, offsA, atomBf, N_ATOMS);
        if (i == 3) break;
        k_bond_conv<<<N_ANG / 64, 256, 0, stream>>>(
            atomBf, bondBf, angleBf, bwbgBf, bga, bgb, idxB,
            bcw1cT + (size_t)i * 64 * 256, bcw1gT + (size_t)i * 64 * 256,
            bcw2cT + (size_t)i * 64 * 64,  bcw2gT + (size_t)i * 64 * 64,
            bcoT   + (size_t)i * 64 * 64,
            bc_cb1 + i * 64, bc_cb2 + i * 64, bc_gb1 + i * 64, bc_gb2 + i * 64, updBuf);
        k_reduce<<<N_UND * 8 / 256, 256, 0, stream>>>(updBuf, offsB, bondBf, N_UND);
        k_angle<<<N_ANG / 64, 256, 0, stream>>>(
            atomBf, bondBf, angleBf, bga, bgb, idxB,
            anwcT + (size_t)i * 64 * 256, anwgT + (size_t)i * 64 * 256,
            an_cb + i * 64, an_gb + i * 64);
    }

    hipMemsetAsync(esum, 0, 128 * 4, stream);
    hipMemsetAsync(cnt,  0, 128 * 4, stream);
    k_readout<<<N_ATOMS * 64 / 256, 256, 0, stream>>>(
        atomBf, owners, ro_w1, ro_b1, ro_w2, ro_b2, ro_w3, ro_b3, esum, cnt);
    k_final<<<1, 128, 0, stream>>>(esum, cnt, (float*)d_out);
}

// Round 11
// 859.384 us; speedup vs baseline: 1.7235x; 1.0134x over previous
//
#include <hip/hip_runtime.h>
#include <hip/hip_bf16.h>

typedef float f32x4 __attribute__((ext_vector_type(4)));
typedef short s16x8 __attribute__((ext_vector_type(8)));
typedef unsigned int u32x4 __attribute__((ext_vector_type(4)));

#define DEV static __device__ __forceinline__

DEV unsigned short f2bf(float x){
    unsigned u = __builtin_bit_cast(unsigned, x);
    u += 0x7FFFu + ((u >> 16) & 1u);
    return (unsigned short)(u >> 16);
}
DEV float bf2f(unsigned short h){
    unsigned u = ((unsigned)h) << 16;
    return __builtin_bit_cast(float, u);
}
DEV float sigm_(float x){ return __builtin_amdgcn_rcpf(1.0f + __expf(-x)); }
DEV float silu_(float x){ return x * sigm_(x); }

DEV int xcd_swz(){
    int bid = blockIdx.x, nwg = gridDim.x;
    return (bid & 7) * (nwg >> 3) + (bid >> 3);
}

// ---------------- weight transpose + convert:  src [B][K][64] f32 -> dst [B][64][K] bf16
__global__ __launch_bounds__(256) void k_transconv(const float* __restrict__ src,
                                                   unsigned short* __restrict__ dst,
                                                   int K, int total){
    int gid = blockIdx.x * 256 + threadIdx.x;
    if (gid >= total) return;
    int kn  = K * 64;
    int b   = gid / kn;
    int rem = gid - b * kn;
    int k   = rem >> 6, n = rem & 63;
    dst[b * kn + n * K + k] = f2bf(src[gid]);
}

// ---------------- atom embedding gather
__global__ __launch_bounds__(256) void k_embed(const float* __restrict__ emb,
                                               const int* __restrict__ z,
                                               unsigned short* __restrict__ out){
    int gid = blockIdx.x * 256 + threadIdx.x;
    int n = gid >> 6, f = gid & 63;
    out[gid] = f2bf(emb[z[n] * 64 + f]);
}

// ---------------- bases[rows][9] @ W[9][64] -> bf16 out[rows][64]
__global__ __launch_bounds__(256) void k_smallmm(const float* __restrict__ bases,
                                                 const float* __restrict__ W,
                                                 unsigned short* __restrict__ out){
    int gid = blockIdx.x * 256 + threadIdx.x;
    int r = gid >> 6, f = gid & 63;
    const float* b = bases + r * 9;
    float acc = 0.f;
    #pragma unroll
    for (int k = 0; k < 9; ++k) acc += b[k] * W[k * 64 + f];
    out[gid] = f2bf(acc);
}

// permuted variant: out[r] = bases[perm[r]] @ W  (angle stored in sorted space)
__global__ __launch_bounds__(256) void k_smallmm_perm(const float* __restrict__ bases,
                                                      const float* __restrict__ W,
                                                      const int* __restrict__ perm,
                                                      unsigned short* __restrict__ out){
    int gid = blockIdx.x * 256 + threadIdx.x;
    int r = gid >> 6, f = gid & 63;
    const float* b = bases + (size_t)perm[r] * 9;
    float acc = 0.f;
    #pragma unroll
    for (int k = 0; k < 9; ++k) acc += b[k] * W[k * 64 + f];
    out[gid] = f2bf(acc);
}

// ---------------- CSR build helpers
__global__ void k_count(const int* __restrict__ dst, int stride, int n, int* __restrict__ cnt){
    int i = blockIdx.x * 256 + threadIdx.x;
    if (i < n) atomicAdd(&cnt[dst[(size_t)i * stride]], 1);
}

__global__ __launch_bounds__(256) void k_bsum(const int* __restrict__ cnt,
                                              int* __restrict__ bsum){
    int i = blockIdx.x * 256 + threadIdx.x;
    int v = cnt[i];
    #pragma unroll
    for (int off = 32; off > 0; off >>= 1) v += __shfl_down(v, off);
    __shared__ int ws[4];
    if ((threadIdx.x & 63) == 0) ws[threadIdx.x >> 6] = v;
    __syncthreads();
    if (threadIdx.x == 0) bsum[blockIdx.x] = ws[0] + ws[1] + ws[2] + ws[3];
}

__global__ __launch_bounds__(256) void k_bscan(const int* __restrict__ bsum,
                                               int* __restrict__ bbase, int nb,
                                               int* __restrict__ total_out){
    __shared__ int sh[256];
    int t = threadIdx.x;
    int v = (t < nb) ? bsum[t] : 0;
    sh[t] = v;
    __syncthreads();
    for (int d = 1; d < 256; d <<= 1){
        int u = (t >= d) ? sh[t - d] : 0;
        __syncthreads();
        sh[t] += u;
        __syncthreads();
    }
    if (t < nb) bbase[t] = sh[t] - v;
    if (t == nb - 1) *total_out = sh[t];
}

__global__ __launch_bounds__(256) void k_offs(const int* __restrict__ cnt,
                                              const int* __restrict__ bbase,
                                              int* __restrict__ offs){
    __shared__ int sh[256];
    int t = threadIdx.x;
    int i = blockIdx.x * 256 + t;
    int v = cnt[i];
    sh[t] = v;
    __syncthreads();
    for (int d = 1; d < 256; d <<= 1){
        int u = (t >= d) ? sh[t - d] : 0;
        __syncthreads();
        sh[t] += u;
        __syncthreads();
    }
    offs[i] = bbase[blockIdx.x] + sh[t] - v;
}

__global__ void k_fill(const int* __restrict__ dst, int stride, int n,
                       const int* __restrict__ offs, int* __restrict__ cur,
                       int* __restrict__ idx){
    int i = blockIdx.x * 256 + threadIdx.x;
    if (i < n){
        int d = dst[(size_t)i * stride];
        int p = offs[d] + atomicAdd(&cur[d], 1);
        idx[p] = i;
    }
}

// ---------------- gather-reduce (contiguous)
__global__ __launch_bounds__(256) void k_reduce(const unsigned short* __restrict__ upd,
                                                const int* __restrict__ offs,
                                                unsigned short* __restrict__ act, int nRows){
    int gid = blockIdx.x * 256 + threadIdx.x;
    int row = gid >> 3;
    if (row >= nRows) return;
    int c8 = (gid & 7) * 8;
    int o = offs[row], e = offs[row + 1];
    float acc[8] = {};
    for (int j = o; j < e; ++j){
        s16x8 v = *(const s16x8*)&upd[(size_t)j * 64 + c8];
        #pragma unroll
        for (int q = 0; q < 8; ++q) acc[q] += bf2f((unsigned short)v[q]);
    }
    s16x8 a = *(s16x8*)&act[(size_t)row * 64 + c8];
    #pragma unroll
    for (int q = 0; q < 8; ++q) a[q] = (short)f2bf(bf2f((unsigned short)a[q]) + acc[q]);
    *(s16x8*)&act[(size_t)row * 64 + c8] = a;
}

#define MFMA16(a,b,c) __builtin_amdgcn_mfma_f32_16x16x32_bf16(a,b,c,0,0,0)

// ================= atom-conv body (shared by standalone + fused kernels) =================
DEV void atom_body(unsigned short* smem, int* ldsSrc, int bid,
    const unsigned short* atomBf, const unsigned short* bondBf,
    const unsigned short* bwagBf,
    const int* agraph, const int* d2u, const int* idxA,
    const unsigned short* w1cT, const unsigned short* w1gT,
    const unsigned short* w2cT, const unsigned short* w2gT,
    const unsigned short* woT,
    const float* cb1, const float* cb2, const float* gb1, const float* gb2,
    unsigned short* upd)
{
    unsigned short* ldsA  = smem;
    unsigned short* ldsHC = smem;
    unsigned short* ldsHG = smem + 4736;
    unsigned short* ldsV  = smem + 9472;
    unsigned short* ldsBw = smem + 14208;   // [64][68]
    const int tid = threadIdx.x;
    const int r0  = bid * 64;

    {   // q: 0=atom[ag0] 1=bond[d2u] 2=atom[ag1] 3=bw[d2u]
        int q = tid >> 6, row = tid & 63;
        int e = idxA[r0 + row];
        int s;
        if (q == 0)      s = agraph[2 * e];
        else if (q == 1) s = d2u[e];
        else if (q == 2) s = agraph[2 * e + 1];
        else             s = d2u[e];
        ldsSrc[tid] = s;
    }
    __syncthreads();
    {
        const int lane8 = tid & 7;
        #pragma unroll
        for (int p = 0; p < 8; ++p){
            int cc = p * 32 + (tid >> 3);
            int q = cc >> 6, row = cc & 63;
            int s = ldsSrc[cc];
            const unsigned short* buf = (q == 1 || q == 3) ? bondBf : atomBf;
            if (q == 3) buf = bwagBf;
            u32x4 v = *(const u32x4*)(buf + (size_t)s * 64 + lane8 * 8);
            if (q < 3) *(u32x4*)&ldsA[row * 200 + q * 64 + lane8 * 8] = v;
            else       *(u32x4*)&ldsBw[row * 68 + lane8 * 8] = v;
        }
    }
    __syncthreads();

    const int lane = tid & 63;
    const int r16  = lane & 15;
    const int grp  = lane >> 4;
    const int col  = (tid >> 6) * 16 + r16;

    f32x4 aC[4] = {}, aG[4] = {};
    #pragma unroll
    for (int kt = 0; kt < 6; ++kt){
        s16x8 bc = *(const s16x8*)&w1cT[col * 192 + kt * 32 + grp * 8];
        s16x8 bg = *(const s16x8*)&w1gT[col * 192 + kt * 32 + grp * 8];
        #pragma unroll
        for (int mt = 0; mt < 4; ++mt){
            s16x8 a = *(const s16x8*)&ldsA[(mt * 16 + r16) * 200 + kt * 32 + grp * 8];
            aC[mt] = MFMA16(a, bc, aC[mt]);
            aG[mt] = MFMA16(a, bg, aG[mt]);
        }
    }
    __syncthreads();   // ldsA dead; overlay writable

    const float bC1 = cb1[col], bG1 = gb1[col];
    #pragma unroll
    for (int mt = 0; mt < 4; ++mt){
        #pragma unroll
        for (int j = 0; j < 4; ++j){
            int row = mt * 16 + grp * 4 + j;
            ldsHC[row * 74 + col] = f2bf(silu_(aC[mt][j] + bC1));
            ldsHG[row * 74 + col] = f2bf(silu_(aG[mt][j] + bG1));
        }
    }
    __syncthreads();

    f32x4 oC[4] = {}, oG[4] = {};
    #pragma unroll
    for (int kt = 0; kt < 2; ++kt){
        s16x8 bc = *(const s16x8*)&w2cT[col * 64 + kt * 32 + grp * 8];
        s16x8 bg = *(const s16x8*)&w2gT[col * 64 + kt * 32 + grp * 8];
        #pragma unroll
        for (int mt = 0; mt < 4; ++mt){
            s16x8 hc = *(const s16x8*)&ldsHC[(mt * 16 + r16) * 74 + kt * 32 + grp * 8];
            s16x8 hg = *(const s16x8*)&ldsHG[(mt * 16 + r16) * 74 + kt * 32 + grp * 8];
            oC[mt] = MFMA16(hc, bc, oC[mt]);
            oG[mt] = MFMA16(hg, bg, oG[mt]);
        }
    }
    const float bC2 = cb2[col], bG2 = gb2[col];
    #pragma unroll
    for (int mt = 0; mt < 4; ++mt){
        #pragma unroll
        for (int j = 0; j < 4; ++j){
            int row = mt * 16 + grp * 4 + j;
            float v = silu_(oC[mt][j] + bC2) * sigm_(oG[mt][j] + bG2);
            v *= bf2f(ldsBw[row * 68 + col]);
            ldsV[row * 74 + col] = f2bf(v);
        }
    }
    __syncthreads();

    f32x4 oD[4] = {};
    #pragma unroll
    for (int kt = 0; kt < 2; ++kt){
        s16x8 bo = *(const s16x8*)&woT[col * 64 + kt * 32 + grp * 8];
        #pragma unroll
        for (int mt = 0; mt < 4; ++mt){
            s16x8 a = *(const s16x8*)&ldsV[(mt * 16 + r16) * 74 + kt * 32 + grp * 8];
            oD[mt] = MFMA16(a, bo, oD[mt]);
        }
    }
    #pragma unroll
    for (int mt = 0; mt < 4; ++mt){
        #pragma unroll
        for (int j = 0; j < 4; ++j){
            int row = mt * 16 + grp * 4 + j;
            upd[(size_t)(r0 + row) * 64 + col] = f2bf(oD[mt][j]);
        }
    }
}

// ================= angle body (angle stored in idxB-sorted space) =================
DEV void angle_body(unsigned short* ldsA, int* ldsSrc, int bid,
    const unsigned short* atomBf, const unsigned short* bondBf,
    unsigned short* angleS,
    const int* bga, const int* bgb, const int* idxB,
    const unsigned short* wcT, const unsigned short* wgT,
    const float* cb, const float* gb)
{
    const int tid = threadIdx.x;
    const int r0  = bid * 64;

    {   // q: 0=bond[bgi] 1=bond[bgj] 2=angle(sorted,contig) 3=atom[bga]
        int q = tid >> 6, row = tid & 63;
        int s;
        if (q == 2) s = r0 + row;
        else {
            int a = idxB[r0 + row];
            if (q == 0)      s = bgb[2 * a];
            else if (q == 1) s = bgb[2 * a + 1];
            else             s = bga[a];
        }
        ldsSrc[tid] = s;
    }
    __syncthreads();
    {
        const int lane8 = tid & 7;
        #pragma unroll
        for (int p = 0; p < 8; ++p){
            int cc = p * 32 + (tid >> 3);
            int q = cc >> 6, row = cc & 63;
            int s = ldsSrc[cc];
            const unsigned short* buf = (q < 2) ? bondBf : (q == 2 ? angleS : atomBf);
            u32x4 v = *(const u32x4*)(buf + (size_t)s * 64 + lane8 * 8);
            *(u32x4*)&ldsA[row * 264 + q * 64 + lane8 * 8] = v;
        }
    }
    __syncthreads();

    const int lane = tid & 63;
    const int r16  = lane & 15;
    const int grp  = lane >> 4;
    const int col  = (tid >> 6) * 16 + r16;

    f32x4 aC[4] = {}, aG[4] = {};
    #pragma unroll
    for (int kt = 0; kt < 8; ++kt){
        s16x8 bc = *(const s16x8*)&wcT[col * 256 + kt * 32 + grp * 8];
        s16x8 bg = *(const s16x8*)&wgT[col * 256 + kt * 32 + grp * 8];
        #pragma unroll
        for (int mt = 0; mt < 4; ++mt){
            s16x8 a = *(const s16x8*)&ldsA[(mt * 16 + r16) * 264 + kt * 32 + grp * 8];
            aC[mt] = MFMA16(a, bc, aC[mt]);
            aG[mt] = MFMA16(a, bg, aG[mt]);
        }
    }
    const float bC = cb[col], bG = gb[col];
    #pragma unroll
    for (int mt = 0; mt < 4; ++mt){
        #pragma unroll
        for (int j = 0; j < 4; ++j){
            int row = mt * 16 + grp * 4 + j;
            float oldv = bf2f(ldsA[row * 264 + 128 + col]);
            float v = silu_(aC[mt][j] + bC) * sigm_(aG[mt][j] + bG);
            angleS[(size_t)(r0 + row) * 64 + col] = f2bf(oldv + v);   // contiguous write
        }
    }
}

// ---------------- standalone atom conv (first iteration)
__global__ __launch_bounds__(256, 4) void k_atom_conv(
    const unsigned short* __restrict__ atomBf, const unsigned short* __restrict__ bondBf,
    const unsigned short* __restrict__ bwagBf,
    const int* __restrict__ agraph, const int* __restrict__ d2u,
    const int* __restrict__ idxA,
    const unsigned short* __restrict__ w1cT, const unsigned short* __restrict__ w1gT,
    const unsigned short* __restrict__ w2cT, const unsigned short* __restrict__ w2gT,
    const unsigned short* __restrict__ woT,
    const float* __restrict__ cb1, const float* __restrict__ cb2,
    const float* __restrict__ gb1, const float* __restrict__ gb2,
    unsigned short* __restrict__ upd)
{
    __shared__ __align__(16) unsigned short smem[18560];
    __shared__ int ldsSrc[256];
    atom_body(smem, ldsSrc, xcd_swz(),
              atomBf, bondBf, bwagBf, agraph, d2u, idxA,
              w1cT, w1gT, w2cT, w2gT, woT, cb1, cb2, gb1, gb2, upd);
}

// ---------------- fused: angle update (iter i) + atom conv (iter i+1), independent work
__global__ __launch_bounds__(256, 4) void k_angle_atom(
    const unsigned short* __restrict__ atomBf, const unsigned short* __restrict__ bondBf,
    unsigned short* __restrict__ angleS, const unsigned short* __restrict__ bwagBf,
    const int* __restrict__ agraph, const int* __restrict__ d2u, const int* __restrict__ idxA,
    const int* __restrict__ bga, const int* __restrict__ bgb, const int* __restrict__ idxB,
    const unsigned short* __restrict__ an_wcT, const unsigned short* __restrict__ an_wgT,
    const float* __restrict__ an_cb, const float* __restrict__ an_gb,
    const unsigned short* __restrict__ ac_w1cT, const unsigned short* __restrict__ ac_w1gT,
    const unsigned short* __restrict__ ac_w2cT, const unsigned short* __restrict__ ac_w2gT,
    const unsigned short* __restrict__ ac_woT,
    const float* __restrict__ ac_cb1, const float* __restrict__ ac_cb2,
    const float* __restrict__ ac_gb1, const float* __restrict__ ac_gb2,
    unsigned short* __restrict__ upd, int nbAngle)
{
    __shared__ __align__(16) unsigned short smem[18560];
    __shared__ int ldsSrc[256];
    int bid = blockIdx.x;
    if (bid < nbAngle){
        angle_body(smem, ldsSrc, bid, atomBf, bondBf, angleS, bga, bgb, idxB,
                   an_wcT, an_wgT, an_cb, an_gb);
    } else {
        atom_body(smem, ldsSrc, bid - nbAngle,
                  atomBf, bondBf, bwagBf, agraph, d2u, idxA,
                  ac_w1cT, ac_w1gT, ac_w2cT, ac_w2gT, ac_woT,
                  ac_cb1, ac_cb2, ac_gb1, ac_gb2, upd);
    }
}

// ---------------- bond conv (angle read from sorted space)
__global__ __launch_bounds__(256, 4) void k_bond_conv(
    const unsigned short* __restrict__ atomBf, const unsigned short* __restrict__ bondBf,
    const unsigned short* __restrict__ angleS, const unsigned short* __restrict__ bwbgBf,
    const int* __restrict__ bga, const int* __restrict__ bgb,
    const int* __restrict__ idxB,
    const unsigned short* __restrict__ w1cT, const unsigned short* __restrict__ w1gT,
    const unsigned short* __restrict__ w2cT, const unsigned short* __restrict__ w2gT,
    const unsigned short* __restrict__ woT,
    const float* __restrict__ cb1, const float* __restrict__ cb2,
    const float* __restrict__ gb1, const float* __restrict__ gb2,
    unsigned short* __restrict__ upd)
{
    __shared__ __align__(16) unsigned short lds[16896];
    __shared__ int ldsSrc[256];
    unsigned short* ldsA  = lds;
    unsigned short* ldsHC = lds;
    unsigned short* ldsHG = lds + 4736;
    unsigned short* ldsV  = lds + 9472;
    const int tid = threadIdx.x;
    const int r0  = xcd_swz() * 64;

    {
        int q = tid >> 6, row = tid & 63;
        int s;
        if (q == 2) s = r0 + row;                 // sorted angle: contiguous
        else {
            int a = idxB[r0 + row];
            if (q == 0)      s = bgb[2 * a];
            else if (q == 1) s = bgb[2 * a + 1];
            else             s = bga[a];
        }
        ldsSrc[tid] = s;
    }
    __syncthreads();
    {
        const int lane8 = tid & 7;
        #pragma unroll
        for (int p = 0; p < 8; ++p){
            int cc = p * 32 + (tid >> 3);
            int q = cc >> 6, row = cc & 63;
            int s = ldsSrc[cc];
            const unsigned short* buf = (q < 2) ? bondBf : (q == 2 ? angleS : atomBf);
            u32x4 v = *(const u32x4*)(buf + (size_t)s * 64 + lane8 * 8);
            *(u32x4*)&ldsA[row * 264 + q * 64 + lane8 * 8] = v;
        }
    }
    __syncthreads();

    const int lane = tid & 63;
    const int r16  = lane & 15;
    const int grp  = lane >> 4;
    const int col  = (tid >> 6) * 16 + r16;

    unsigned short bwv[16];
    #pragma unroll
    for (int mt = 0; mt < 4; ++mt)
        #pragma unroll
        for (int j = 0; j < 4; ++j)
            bwv[mt * 4 + j] = bwbgBf[(size_t)ldsSrc[mt * 16 + grp * 4 + j] * 64 + col];

    f32x4 aC[4] = {}, aG[4] = {};
    #pragma unroll
    for (int kt = 0; kt < 8; ++kt){
        s16x8 bc = *(const s16x8*)&w1cT[col * 256 + kt * 32 + grp * 8];
        s16x8 bg = *(const s16x8*)&w1gT[col * 256 + kt * 32 + grp * 8];
        #pragma unroll
        for (int mt = 0; mt < 4; ++mt){
            s16x8 a = *(const s16x8*)&ldsA[(mt * 16 + r16) * 264 + kt * 32 + grp * 8];
            aC[mt] = MFMA16(a, bc, aC[mt]);
            aG[mt] = MFMA16(a, bg, aG[mt]);
        }
    }
    __syncthreads();

    const float bC1 = cb1[col], bG1 = gb1[col];
    #pragma unroll
    for (int mt = 0; mt < 4; ++mt){
        #pragma unroll
        for (int j = 0; j < 4; ++j){
            int row = mt * 16 + grp * 4 + j;
            ldsHC[row * 74 + col] = f2bf(silu_(aC[mt][j] + bC1));
            ldsHG[row * 74 + col] = f2bf(silu_(aG[mt][j] + bG1));
        }
    }
    __syncthreads();

    f32x4 oC[4] = {}, oG[4] = {};
    #pragma unroll
    for (int kt = 0; kt < 2; ++kt){
        s16x8 bc = *(const s16x8*)&w2cT[col * 64 + kt * 32 + grp * 8];
        s16x8 bg = *(const s16x8*)&w2gT[col * 64 + kt * 32 + grp * 8];
        #pragma unroll
        for (int mt = 0; mt < 4; ++mt){
            s16x8 hc = *(const s16x8*)&ldsHC[(mt * 16 + r16) * 74 + kt * 32 + grp * 8];
            s16x8 hg = *(const s16x8*)&ldsHG[(mt * 16 + r16) * 74 + kt * 32 + grp * 8];
            oC[mt] = MFMA16(hc, bc, oC[mt]);
            oG[mt] = MFMA16(hg, bg, oG[mt]);
        }
    }
    const float bC2 = cb2[col], bG2 = gb2[col];
    #pragma unroll
    for (int mt = 0; mt < 4; ++mt){
        #pragma unroll
        for (int j = 0; j < 4; ++j){
            int row = mt * 16 + grp * 4 + j;
            float v = silu_(oC[mt][j] + bC2) * sigm_(oG[mt][j] + bG2);
            v *= bf2f(bwv[mt * 4 + j]);
            ldsV[row * 74 + col] = f2bf(v);
        }
    }
    __syncthreads();

    f32x4 oD[4] = {};
    #pragma unroll
    for (int kt = 0; kt < 2; ++kt){
        s16x8 bo = *(const s16x8*)&woT[col * 64 + kt * 32 + grp * 8];
        #pragma unroll
        for (int mt = 0; mt < 4; ++mt){
            s16x8 a = *(const s16x8*)&ldsV[(mt * 16 + r16) * 74 + kt * 32 + grp * 8];
            oD[mt] = MFMA16(a, bo, oD[mt]);
        }
    }
    #pragma unroll
    for (int mt = 0; mt < 4; ++mt){
        #pragma unroll
        for (int j = 0; j < 4; ++j){
            int row = mt * 16 + grp * 4 + j;
            upd[(size_t)(r0 + row) * 64 + col] = f2bf(oD[mt][j]);
        }
    }
}

// ---------------- readout MLP + segmented sum (wave per atom row)
__global__ __launch_bounds__(256) void k_readout(
    const unsigned short* __restrict__ atomBf, const int* __restrict__ owners,
    const float* __restrict__ w1, const float* __restrict__ b1,
    const float* __restrict__ w2, const float* __restrict__ b2,
    const float* __restrict__ w3, const float* __restrict__ b3,
    float* __restrict__ esum, float* __restrict__ cnt)
{
    int gid  = blockIdx.x * 256 + threadIdx.x;
    int n    = gid >> 6;
    int lane = threadIdx.x & 63;
    float a = bf2f(atomBf[n * 64 + lane]);
    float acc = b1[lane];
    #pragma unroll
    for (int k = 0; k < 64; ++k) acc += __shfl(a, k) * w1[k * 64 + lane];
    float h = silu_(acc);
    acc = b2[lane];
    #pragma unroll
    for (int k = 0; k < 64; ++k) acc += __shfl(h, k) * w2[k * 64 + lane];
    h = silu_(acc);
    float p = h * w3[lane];
    #pragma unroll
    for (int off = 32; off > 0; off >>= 1) p += __shfl_xor(p, off);
    if (lane == 0){
        atomicAdd(&esum[owners[n]], p + b3[0]);
        atomicAdd(&cnt[owners[n]], 1.0f);
    }
}

__global__ void k_final(const float* __restrict__ esum, const float* __restrict__ cnt,
                        float* __restrict__ out){
    int i = threadIdx.x;
    if (i < 128) out[i] = esum[i] / fmaxf(cnt[i], 1.0f);
}

extern "C" void kernel_launch(void* const* d_in, const int* in_sizes, int n_in,
                              void* d_out, int out_size, void* d_ws, size_t ws_size,
                              hipStream_t stream)
{
    (void)in_sizes; (void)n_in; (void)out_size; (void)ws_size;
    const int N_ATOMS = 8192, N_UND = 65536, N_DIR = 131072, N_ANG = 262144;

    const int*   atomic_numbers = (const int*)  d_in[0];
    const float* bb_ag  = (const float*)d_in[1];
    const float* bb_bg  = (const float*)d_in[2];
    const float* ang_b  = (const float*)d_in[3];
    const int*   agraph = (const int*)  d_in[4];
    const int*   d2u    = (const int*)  d_in[5];
    const int*   bga    = (const int*)  d_in[6];
    const int*   bgb    = (const int*)  d_in[7];
    const int*   owners = (const int*)  d_in[8];
    const float* emb    = (const float*)d_in[9];
    const float* Wb     = (const float*)d_in[10];
    const float* Wa     = (const float*)d_in[11];
    const float* Wbwag  = (const float*)d_in[12];
    const float* Wbwbg  = (const float*)d_in[13];
    const float* ac_cw1 = (const float*)d_in[14];
    const float* ac_cb1 = (const float*)d_in[15];
    const float* ac_cw2 = (const float*)d_in[16];
    const float* ac_cb2 = (const float*)d_in[17];
    const float* ac_gw1 = (const float*)d_in[18];
    const float* ac_gb1 = (const float*)d_in[19];
    const float* ac_gw2 = (const float*)d_in[20];
    const float* ac_gb2 = (const float*)d_in[21];
    const float* ac_out = (const float*)d_in[22];
    const float* bc_cw1 = (const float*)d_in[23];
    const float* bc_cb1 = (const float*)d_in[24];
    const float* bc_cw2 = (const float*)d_in[25];
    const float* bc_cb2 = (const float*)d_in[26];
    const float* bc_gw1 = (const float*)d_in[27];
    const float* bc_gb1 = (const float*)d_in[28];
    const float* bc_gw2 = (const float*)d_in[29];
    const float* bc_gb2 = (const float*)d_in[30];
    const float* bc_out = (const float*)d_in[31];
    const float* an_cw  = (const float*)d_in[32];
    const float* an_cb  = (const float*)d_in[33];
    const float* an_gw  = (const float*)d_in[34];
    const float* an_gb  = (const float*)d_in[35];
    const float* ro_w1  = (const float*)d_in[36];
    const float* ro_b1  = (const float*)d_in[37];
    const float* ro_w2  = (const float*)d_in[38];
    const float* ro_b2  = (const float*)d_in[39];
    const float* ro_w3  = (const float*)d_in[40];
    const float* ro_b3  = (const float*)d_in[41];

    char* ws = (char*)d_ws;
    size_t off = 0;
    auto alloc = [&](size_t bytes) -> void* {
        void* p = ws + off;
        off = (off + bytes + 255) & ~(size_t)255;
        return p;
    };
    unsigned short* atomBf  = (unsigned short*)alloc((size_t)N_ATOMS * 64 * 2);
    unsigned short* bondBf  = (unsigned short*)alloc((size_t)N_UND   * 64 * 2);
    unsigned short* angleS  = (unsigned short*)alloc((size_t)N_ANG   * 64 * 2);
    unsigned short* bwagBf  = (unsigned short*)alloc((size_t)N_UND   * 64 * 2);
    unsigned short* bwbgBf  = (unsigned short*)alloc((size_t)N_UND   * 64 * 2);
    unsigned short* updBuf  = (unsigned short*)alloc((size_t)N_ANG   * 64 * 2);
    float* esum   = (float*)alloc(128 * 4);
    float* cnt    = (float*)alloc(128 * 4);
    int* offsA = (int*)alloc((N_ATOMS + 1) * 4);
    int* curA  = (int*)alloc(N_ATOMS * 4);
    int* idxA  = (int*)alloc((size_t)N_DIR * 4);
    int* offsB = (int*)alloc((N_UND + 1) * 4);
    int* curB  = (int*)alloc(N_UND * 4);
    int* idxB  = (int*)alloc((size_t)N_ANG * 4);
    int* bsum  = (int*)alloc(256 * 4);
    int* bbase = (int*)alloc(256 * 4);
    unsigned short* acw1cT = (unsigned short*)alloc((size_t)4 * 64 * 192 * 2);
    unsigned short* acw1gT = (unsigned short*)alloc((size_t)4 * 64 * 192 * 2);
    unsigned short* acw2cT = (unsigned short*)alloc((size_t)4 * 64 * 64 * 2);
    unsigned short* acw2gT = (unsigned short*)alloc((size_t)4 * 64 * 64 * 2);
    unsigned short* acoT   = (unsigned short*)alloc((size_t)4 * 64 * 64 * 2);
    unsigned short* bcw1cT = (unsigned short*)alloc((size_t)3 * 64 * 256 * 2);
    unsigned short* bcw1gT = (unsigned short*)alloc((size_t)3 * 64 * 256 * 2);
    unsigned short* bcw2cT = (unsigned short*)alloc((size_t)3 * 64 * 64 * 2);
    unsigned short* bcw2gT = (unsigned short*)alloc((size_t)3 * 64 * 64 * 2);
    unsigned short* bcoT   = (unsigned short*)alloc((size_t)3 * 64 * 64 * 2);
    unsigned short* anwcT  = (unsigned short*)alloc((size_t)3 * 64 * 256 * 2);
    unsigned short* anwgT  = (unsigned short*)alloc((size_t)3 * 64 * 256 * 2);

    // CSR build first (idxB needed by permuted angle init)
    hipMemsetAsync(curA, 0, N_ATOMS * 4, stream);
    k_count<<<(N_DIR + 255) / 256, 256, 0, stream>>>(agraph, 2, N_DIR, curA);
    k_bsum <<<N_ATOMS / 256, 256, 0, stream>>>(curA, bsum);
    k_bscan<<<1, 256, 0, stream>>>(bsum, bbase, N_ATOMS / 256, offsA + N_ATOMS);
    k_offs <<<N_ATOMS / 256, 256, 0, stream>>>(curA, bbase, offsA);
    hipMemsetAsync(curA, 0, N_ATOMS * 4, stream);
    k_fill<<<(N_DIR + 255) / 256, 256, 0, stream>>>(agraph, 2, N_DIR, offsA, curA, idxA);

    hipMemsetAsync(curB, 0, N_UND * 4, stream);
    k_count<<<(N_ANG + 255) / 256, 256, 0, stream>>>(bgb, 2, N_ANG, curB);
    k_bsum <<<N_UND / 256, 256, 0, stream>>>(curB, bsum);
    k_bscan<<<1, 256, 0, stream>>>(bsum, bbase, N_UND / 256, offsB + N_UND);
    k_offs <<<N_UND / 256, 256, 0, stream>>>(curB, bbase, offsB);
    hipMemsetAsync(curB, 0, N_UND * 4, stream);
    k_fill<<<(N_ANG + 255) / 256, 256, 0, stream>>>(bgb, 2, N_ANG, offsB, curB, idxB);

    auto tc = [&](const float* src, unsigned short* dst, int B, int K){
        int total = B * K * 64;
        k_transconv<<<(total + 255) / 256, 256, 0, stream>>>(src, dst, K, total);
    };
    tc(ac_cw1, acw1cT, 4, 192);  tc(ac_gw1, acw1gT, 4, 192);
    tc(ac_cw2, acw2cT, 4, 64);   tc(ac_gw2, acw2gT, 4, 64);
    tc(ac_out, acoT,   4, 64);
    tc(bc_cw1, bcw1cT, 3, 256);  tc(bc_gw1, bcw1gT, 3, 256);
    tc(bc_cw2, bcw2cT, 3, 64);   tc(bc_gw2, bcw2gT, 3, 64);
    tc(bc_out, bcoT,   3, 64);
    tc(an_cw,  anwcT,  3, 256);  tc(an_gw,  anwgT,  3, 256);

    k_embed<<<N_ATOMS * 64 / 256, 256, 0, stream>>>(emb, atomic_numbers, atomBf);
    k_smallmm<<<N_UND * 64 / 256, 256, 0, stream>>>(bb_ag, Wb,    bondBf);
    k_smallmm_perm<<<N_ANG * 64 / 256, 256, 0, stream>>>(ang_b, Wa, idxB, angleS);
    k_smallmm<<<N_UND * 64 / 256, 256, 0, stream>>>(bb_ag, Wbwag, bwagBf);
    k_smallmm<<<N_UND * 64 / 256, 256, 0, stream>>>(bb_bg, Wbwbg, bwbgBf);

    // iteration 0 atom conv
    k_atom_conv<<<N_DIR / 64, 256, 0, stream>>>(
        atomBf, bondBf, bwagBf, agraph, d2u, idxA,
        acw1cT, acw1gT, acw2cT, acw2gT, acoT,
        ac_cb1, ac_cb2, ac_gb1, ac_gb2, updBuf);
    k_reduce<<<N_ATOMS * 8 / 256, 256, 0, stream>>>(updBuf, offsA, atomBf, N_ATOMS);

    const int NB_AN = N_ANG / 64;      // 4096
    const int NB_AC = N_DIR / 64;      // 2048
    for (int i = 0; i < 3; ++i){
        k_bond_conv<<<NB_AN, 256, 0, stream>>>(
            atomBf, bondBf, angleS, bwbgBf, bga, bgb, idxB,
            bcw1cT + (size_t)i * 64 * 256, bcw1gT + (size_t)i * 64 * 256,
            bcw2cT + (size_t)i * 64 * 64,  bcw2gT + (size_t)i * 64 * 64,
            bcoT   + (size_t)i * 64 * 64,
            bc_cb1 + i * 64, bc_cb2 + i * 64, bc_gb1 + i * 64, bc_gb2 + i * 64, updBuf);
        k_reduce<<<N_UND * 8 / 256, 256, 0, stream>>>(updBuf, offsB, bondBf, N_UND);
        // fused: angle update (iter i)  ||  atom conv (iter i+1) — independent
        k_angle_atom<<<NB_AN + NB_AC, 256, 0, stream>>>(
            atomBf, bondBf, angleS, bwagBf,
            agraph, d2u, idxA, bga, bgb, idxB,
            anwcT + (size_t)i * 64 * 256, anwgT + (size_t)i * 64 * 256,
            an_cb + i * 64, an_gb + i * 64,
            acw1cT + (size_t)(i + 1) * 64 * 192, acw1gT + (size_t)(i + 1) * 64 * 192,
            acw2cT + (size_t)(i + 1) * 64 * 64,  acw2gT + (size_t)(i + 1) * 64 * 64,
            acoT   + (size_t)(i + 1) * 64 * 64,
            ac_cb1 + (i + 1) * 64, ac_cb2 + (i + 1) * 64,
            ac_gb1 + (i + 1) * 64, ac_gb2 + (i + 1) * 64,
            updBuf, NB_AN);
        k_reduce<<<N_ATOMS * 8 / 256, 256, 0, stream>>>(updBuf, offsA, atomBf, N_ATOMS);
    }

    hipMemsetAsync(esum, 0, 128 * 4, stream);
    hipMemsetAsync(cnt,  0, 128 * 4, stream);
    k_readout<<<N_ATOMS * 64 / 256, 256, 0, stream>>>(
        atomBf, owners, ro_w1, ro_b1, ro_w2, ro_b2, ro_w3, ro_b3, esum, cnt);
    k_final<<<1, 128, 0, stream>>>(esum, cnt, (float*)d_out);
}